// Round 9
// baseline (1869.819 us; speedup 1.0000x reference)
//
#include <hip/hip_runtime.h>
#include <math.h>

#define BB 2
#define SS 2048
#define EE 512
#define HH 8
#define HD 64
#define LL 4
#define VV 50257
#define NTOK (BB*SS)
#define VPAD 50304   // 393 * 128

typedef __bf16 bf16_t;
typedef bf16_t bf16x8 __attribute__((ext_vector_type(8)));
typedef float  f32x4  __attribute__((ext_vector_type(4)));

__device__ __forceinline__ void gload_lds16(const void* g, void* l) {
  __builtin_amdgcn_global_load_lds(
      (const __attribute__((address_space(1))) void*)g,
      (__attribute__((address_space(3))) void*)l, 16, 0, 0);
}

// ---------------- embedding + sinusoidal PE ----------------
__global__ __launch_bounds__(256) void embed_kernel(const int* __restrict__ ids,
                                                    const float* __restrict__ emb,
                                                    float* __restrict__ x) {
  int idx = blockIdx.x * 256 + threadIdx.x;
  int e   = idx & (EE - 1);
  int tok = idx >> 9;
  int s   = tok & (SS - 1);
  int id  = ids[tok];
  float freq = expf((float)(e & ~1) * -0.01798894604f);
  float ang  = (float)s * freq;
  float pe   = (e & 1) ? cosf(ang) : sinf(ang);
  x[idx] = emb[(size_t)id * EE + e] + pe;
}

// ---------------- LayerNorm: fp32 in -> bf16 out, one wave per row ----------------
__global__ __launch_bounds__(256) void ln_kernel(const float* __restrict__ in,
                                                 bf16_t* __restrict__ out,
                                                 const float* __restrict__ g,
                                                 const float* __restrict__ b) {
  int wv = threadIdx.x >> 6, lane = threadIdx.x & 63;
  int row = blockIdx.x * 4 + wv;
  const float4* r = reinterpret_cast<const float4*>(in + (size_t)row * EE) + lane * 2;
  float4 v0 = r[0], v1 = r[1];
  float s = v0.x + v0.y + v0.z + v0.w + v1.x + v1.y + v1.z + v1.w;
#pragma unroll
  for (int o = 32; o > 0; o >>= 1) s += __shfl_xor(s, o);
  float mean = s * (1.f / EE);
  float d0 = v0.x-mean, d1 = v0.y-mean, d2 = v0.z-mean, d3 = v0.w-mean;
  float d4 = v1.x-mean, d5 = v1.y-mean, d6 = v1.z-mean, d7 = v1.w-mean;
  float var = d0*d0+d1*d1+d2*d2+d3*d3+d4*d4+d5*d5+d6*d6+d7*d7;
#pragma unroll
  for (int o = 32; o > 0; o >>= 1) var += __shfl_xor(var, o);
  float inv = rsqrtf(var * (1.f / EE) + 1e-5f);
  const float4* gp = reinterpret_cast<const float4*>(g) + lane * 2;
  const float4* bp = reinterpret_cast<const float4*>(b) + lane * 2;
  float4 g0 = gp[0], g1 = gp[1], b0 = bp[0], b1 = bp[1];
  bf16_t tmp[8];
  tmp[0] = (bf16_t)(d0*inv*g0.x + b0.x); tmp[1] = (bf16_t)(d1*inv*g0.y + b0.y);
  tmp[2] = (bf16_t)(d2*inv*g0.z + b0.z); tmp[3] = (bf16_t)(d3*inv*g0.w + b0.w);
  tmp[4] = (bf16_t)(d4*inv*g1.x + b1.x); tmp[5] = (bf16_t)(d5*inv*g1.y + b1.y);
  tmp[6] = (bf16_t)(d6*inv*g1.z + b1.z); tmp[7] = (bf16_t)(d7*inv*g1.w + b1.w);
  *reinterpret_cast<bf16x8*>(out + (size_t)row * EE + lane * 8) = *reinterpret_cast<bf16x8*>(tmp);
}

// ---------------- weight transpose+convert: fp32 [K][N] -> bf16 [N][K] ----------------
__device__ __forceinline__ void transpose_tile(const float* __restrict__ ip,
                                               bf16_t* __restrict__ op,
                                               int k0, int n0, int ldin, int ldout,
                                               int Nvalid, float* T) {
  int t = threadIdx.x;
  int r = t >> 2, cb = (t & 3) * 16;
#pragma unroll
  for (int i = 0; i < 16; i++) {
    int n = n0 + cb + i;
    T[r * 65 + cb + i] = (n < Nvalid) ? ip[(size_t)(k0 + r) * ldin + n] : 0.f;
  }
  __syncthreads();
  bf16_t tmp[16];
#pragma unroll
  for (int i = 0; i < 16; i++) tmp[i] = (bf16_t)T[(cb + i) * 65 + r];
  bf16_t* o = op + (size_t)(n0 + r) * ldout + k0 + cb;
  *reinterpret_cast<bf16x8*>(o)     = *reinterpret_cast<bf16x8*>(&tmp[0]);
  *reinterpret_cast<bf16x8*>(o + 8) = *reinterpret_cast<bf16x8*>(&tmp[8]);
}

__global__ __launch_bounds__(256) void wconv_kernel(const float* __restrict__ in,
                                                    bf16_t* __restrict__ out,
                                                    int ldin, int ldout, int Nvalid,
                                                    long zin, long zout) {
  __shared__ float T[64 * 65];
  transpose_tile(in + (size_t)blockIdx.z * zin, out + (size_t)blockIdx.z * zout,
                 blockIdx.x * 64, blockIdx.y * 64, ldin, ldout, Nvalid, T);
}

__global__ __launch_bounds__(256) void wconv_qkv_kernel(const float* __restrict__ Wq,
                                                        const float* __restrict__ Wk,
                                                        const float* __restrict__ Wv,
                                                        bf16_t* __restrict__ out) {
  __shared__ float T[64 * 65];
  int z = blockIdx.z;
  int l = z / 24, rem = z % 24, sec = rem >> 3, h = rem & 7;
  const float* W = sec == 0 ? Wq : (sec == 1 ? Wk : Wv);
  const float* ip = W + (size_t)(l * 8 + h) * (EE * HD);
  bf16_t* op = out + (size_t)l * (1536 * 512) + (size_t)(sec * 512 + h * 64) * 512;
  transpose_tile(ip, op, blockIdx.x * 64, 0, HD, EE, HD, T);
}

// ---------------- 64/128-tile bf16 MFMA GEMM (layer GEMMs), single-buffer ----
// Fragment-major LDS (0 conflicts). TM=64 -> 24KB LDS, more blocks/CU (TLP).
// MODE: 0=QKV scatter, 1=bias+GELU->bf16, 2=(+bias)+residual f32.
template<int MODE, int TM>
__global__ __launch_bounds__(256) void gemm_bf16(
    const bf16_t* __restrict__ A, const bf16_t* __restrict__ Bt,
    int M, int N, int K,
    const float* __restrict__ bias,
    float* __restrict__ Cf, bf16_t* __restrict__ Cb,
    bf16_t* __restrict__ qo, bf16_t* __restrict__ ko, bf16_t* __restrict__ vo) {
  constexpr int MI = TM / 32;
  __shared__ __align__(16) bf16_t As[TM * 64];
  __shared__ __align__(16) bf16_t Bs[128 * 64];
  int tid = threadIdx.x, lane = tid & 63, w = tid >> 6;
  int lr = lane & 15, lg = lane >> 4;
  int m0 = blockIdx.y * TM, n0 = blockIdx.x * 128;
  f32x4 acc[MI][4];
#pragma unroll
  for (int i = 0; i < MI; i++)
#pragma unroll
    for (int j = 0; j < 4; j++) acc[i][j] = (f32x4){0.f, 0.f, 0.f, 0.f};
  int wr = w >> 1, wc = w & 1;

  const bf16_t* Abase = A  + (size_t)(m0 + lr) * K + lg * 8;
  const bf16_t* Bbase = Bt + (size_t)(n0 + lr) * K + lg * 8;

  for (int k0 = 0; k0 < K; k0 += 64) {
#pragma unroll
    for (int i = 0; i < MI; i++) {
      int c = w * MI + i;
      gload_lds16(Abase + (size_t)(c >> 1) * 16 * K + k0 + (c & 1) * 32,
                  (char*)As + c * 1024);
    }
#pragma unroll
    for (int i = 0; i < 4; i++) {
      int c = w * 4 + i;
      gload_lds16(Bbase + (size_t)(c >> 1) * 16 * K + k0 + (c & 1) * 32,
                  (char*)Bs + c * 1024);
    }
    __syncthreads();
#pragma unroll
    for (int kk = 0; kk < 2; kk++) {
      bf16x8 afr[MI], bfr[4];
#pragma unroll
      for (int mi = 0; mi < MI; mi++)
        afr[mi] = *reinterpret_cast<const bf16x8*>(
            &As[(((wr * MI + mi) << 1) + kk) * 512 + lane * 8]);
#pragma unroll
      for (int ni = 0; ni < 4; ni++)
        bfr[ni] = *reinterpret_cast<const bf16x8*>(
            &Bs[(((wc * 4 + ni) << 1) + kk) * 512 + lane * 8]);
#pragma unroll
      for (int mi = 0; mi < MI; mi++)
#pragma unroll
        for (int ni = 0; ni < 4; ni++)
          acc[mi][ni] = __builtin_amdgcn_mfma_f32_16x16x32_bf16(afr[mi], bfr[ni], acc[mi][ni], 0, 0, 0);
    }
    __syncthreads();
  }

#pragma unroll
  for (int mi = 0; mi < MI; mi++)
#pragma unroll
    for (int ni = 0; ni < 4; ni++) {
      int colg = n0 + wc * 64 + ni * 16 + lr;
#pragma unroll
      for (int j = 0; j < 4; j++) {
        int rowg = m0 + wr * (TM / 2) + mi * 16 + lg * 4 + j;
        float v = acc[mi][ni][j];
        if (MODE == 0) {
          int sec = colg >> 9, cc = colg & 511, hh = cc >> 6, dd = cc & 63;
          int bi = rowg >> 11, s = rowg & 2047;
          if (sec == 0)      qo[(((size_t)bi * HH + hh) * SS + s) * HD + dd] = (bf16_t)(v * 0.125f);
          else if (sec == 1) ko[(((size_t)bi * HH + hh) * SS + s) * HD + dd] = (bf16_t)v;
          else               vo[(((size_t)bi * HH + hh) * HD + dd) * SS + s] = (bf16_t)v;
        } else if (MODE == 1) {
          v += bias[colg];
          v = 0.5f * v * (1.f + erff(v * 0.70710678f));
          Cb[(size_t)rowg * N + colg] = (bf16_t)v;
        } else {
          if (bias) v += bias[colg];
          Cf[(size_t)rowg * EE + colg] += v;
        }
      }
    }
}

// ---------------- vocab GEMM: B-panel resident in LDS, stream A, loop M -------
// One block per 128-col B panel (grid 393). B panel 128x512 bf16 = 128KB LDS,
// loaded ONCE -> B read exactly once from HBM chip-wide (50MB). A (4MB) streams
// via 2x16KB dbuf (L3-resident across blocks). Writes (832MB) interleave per
// M-tile -> kernel approaches the 140us HBM write floor. LDS = 160KB (AITER-proven).
__global__ __launch_bounds__(512) void gemm_vocab(
    const bf16_t* __restrict__ A, const bf16_t* __restrict__ Bt,
    const float* __restrict__ bias, float* __restrict__ C) {
  __shared__ __align__(16) bf16_t Bp[128 * 512];      // 128 KB resident
  __shared__ __align__(16) bf16_t As[2][128 * 64];    // 32 KB dbuf
  int tid = threadIdx.x, lane = tid & 63, w = tid >> 6;
  int lr = lane & 15, lg = lane >> 4;
  int n0 = blockIdx.x * 128;
  int wr = w >> 2, wc = w & 3;    // 2 x 4 wave grid over 128x128 tile

  // ---- load B panel once: 128 x 1KB fragment sub-blocks (cg=wave, kh=0..15)
  const bf16_t* Bbase = Bt + (size_t)(n0 + lr) * 512 + lg * 8;
#pragma unroll
  for (int i = 0; i < 16; i++) {
    int c = w * 16 + i;                       // cg = w, kh = i
    gload_lds16(Bbase + (size_t)w * 16 * 512 + i * 32, (char*)Bp + c * 1024);
  }
  const bf16_t* Abase = A + (size_t)lr * 512 + lg * 8;
  // A chunk s = m*8+ks: 16 sub-blocks (rg 0..7 x kk 0..1), 2 per wave
  auto stageA = [&](int buf, int s) {
    int m = s >> 3, ks = s & 7;
#pragma unroll
    for (int i = 0; i < 2; i++) {
      int c = w * 2 + i;
      gload_lds16(Abase + (size_t)(m * 128 + (c >> 1) * 16) * 512 + ks * 64 + (c & 1) * 32,
                  (char*)&As[buf][0] + c * 1024);
    }
  };
  stageA(0, 0);
  asm volatile("s_waitcnt vmcnt(0)" ::: "memory");
  __syncthreads();

  // hoist bias (column-fixed per thread)
  float bs[2];
  int col0 = n0 + (wc * 2) * 16 + lr;
  int col1 = n0 + (wc * 2 + 1) * 16 + lr;
  bs[0] = (col0 < VV) ? bias[col0] : 0.f;
  bs[1] = (col1 < VV) ? bias[col1] : 0.f;

  for (int m = 0; m < 32; m++) {
    f32x4 acc[4][2];
#pragma unroll
    for (int i = 0; i < 4; i++)
#pragma unroll
      for (int j = 0; j < 2; j++) acc[i][j] = (f32x4){0.f, 0.f, 0.f, 0.f};

#pragma unroll
    for (int ks = 0; ks < 8; ks++) {
      int s = (m << 3) + ks;
      int buf = s & 1;
      if (s + 1 < 256) {
        stageA(buf ^ 1, s + 1);
        asm volatile("s_waitcnt vmcnt(2)" ::: "memory");  // chunk s landed; s+1 flies
      } else {
        asm volatile("s_waitcnt vmcnt(0)" ::: "memory");
      }
      asm volatile("s_barrier" ::: "memory");
      bf16x8 af[4][2], bfr[2][2];
#pragma unroll
      for (int mi = 0; mi < 4; mi++)
#pragma unroll
        for (int kk = 0; kk < 2; kk++)
          af[mi][kk] = *reinterpret_cast<const bf16x8*>(
              &As[buf][(((wr * 4 + mi) << 1) + kk) * 512 + lane * 8]);
#pragma unroll
      for (int ni = 0; ni < 2; ni++)
#pragma unroll
        for (int kk = 0; kk < 2; kk++)
          bfr[ni][kk] = *reinterpret_cast<const bf16x8*>(
              &Bp[(((wc * 2 + ni) << 4) + (ks << 1) + kk) * 512 + lane * 8]);
      __builtin_amdgcn_s_setprio(1);
#pragma unroll
      for (int mi = 0; mi < 4; mi++)
#pragma unroll
        for (int ni = 0; ni < 2; ni++)
#pragma unroll
          for (int kk = 0; kk < 2; kk++)
            acc[mi][ni] = __builtin_amdgcn_mfma_f32_16x16x32_bf16(
                af[mi][kk], bfr[ni][kk], acc[mi][ni], 0, 0, 0);
      __builtin_amdgcn_s_setprio(0);
      asm volatile("s_barrier" ::: "memory");   // reads done before buf overwrite
    }

    // epilogue for this M-tile (overlaps next chunk's in-flight loads)
#pragma unroll
    for (int ni = 0; ni < 2; ni++) {
      int colg = ni ? col1 : col0;
      if (colg < VV) {
#pragma unroll
        for (int mi = 0; mi < 4; mi++)
#pragma unroll
          for (int j = 0; j < 4; j++) {
            int rowg = m * 128 + wr * 64 + mi * 16 + lg * 4 + j;
            C[(size_t)rowg * VV + colg] = acc[mi][ni][j] + bs[ni];
          }
      }
    }
  }
}

// ---------------- flash attention: QBLK=128 q-rows/block, KVB=64 tiles ----------------
#define QBLK 128
#define KVB 64
__global__ __launch_bounds__(256) void attn_kernel(
    const bf16_t* __restrict__ qb,   // [B,H,S,D], pre-scaled by 1/8
    const bf16_t* __restrict__ kb,   // [B,H,S,D]
    const bf16_t* __restrict__ vT,   // [B,H,D,S]
    const int* __restrict__ amask,   // [B,S]
    bf16_t* __restrict__ ab) {       // [B*S][E]
  __shared__ bf16_t Qs[QBLK][72];
  __shared__ bf16_t Ks[KVB][72];
  __shared__ bf16_t Vs[HD][72];
  __shared__ bf16_t Ps[QBLK][72];
  __shared__ float  km[KVB];
  int tid = threadIdx.x, lane = tid & 63, w = tid >> 6;
  int lr = lane & 15, lg = lane >> 4;
  int q0 = blockIdx.x * QBLK, bh = blockIdx.y, b = bh >> 3, h = bh & 7;
  const bf16_t* Qg = qb + (size_t)bh * SS * HD;
  const bf16_t* Kg = kb + (size_t)bh * SS * HD;
  const bf16_t* Vg = vT + (size_t)bh * HD * SS;

  { // stage Q tile
    int r = tid >> 1, c = (tid & 1) * 32;
    const uint4* s = reinterpret_cast<const uint4*>(Qg + (size_t)(q0 + r) * HD + c);
    uint4 a0 = s[0], a1 = s[1], a2 = s[2], a3 = s[3];
    *reinterpret_cast<uint4*>(&Qs[r][c])      = a0;
    *reinterpret_cast<uint4*>(&Qs[r][c + 8])  = a1;
    *reinterpret_cast<uint4*>(&Qs[r][c + 16]) = a2;
    *reinterpret_cast<uint4*>(&Qs[r][c + 24]) = a3;
  }

  f32x4 o[2][4];
  f32x4 m_run[2], l_run[2];
#pragma unroll
  for (int mq = 0; mq < 2; mq++) {
    m_run[mq] = (f32x4){-1e30f, -1e30f, -1e30f, -1e30f};
    l_run[mq] = (f32x4){0.f, 0.f, 0.f, 0.f};
#pragma unroll
    for (int nd = 0; nd < 4; nd++) o[mq][nd] = (f32x4){0.f, 0.f, 0.f, 0.f};
  }

  int ntile = (q0 >> 6) + 2;
  for (int t = 0; t < ntile; t++) {
    int kv0 = t * KVB;
    { // stage K, V^T, mask
      int r = tid >> 2, c = (tid & 3) * 16;
      const uint4* s = reinterpret_cast<const uint4*>(Kg + (size_t)(kv0 + r) * HD + c);
      uint4 x0 = s[0], x1 = s[1];
      *reinterpret_cast<uint4*>(&Ks[r][c])     = x0;
      *reinterpret_cast<uint4*>(&Ks[r][c + 8]) = x1;
      const uint4* sv = reinterpret_cast<const uint4*>(Vg + (size_t)r * SS + kv0 + c);
      uint4 y0 = sv[0], y1 = sv[1];
      *reinterpret_cast<uint4*>(&Vs[r][c])     = y0;
      *reinterpret_cast<uint4*>(&Vs[r][c + 8]) = y1;
      if (tid < KVB) km[tid] = amask[b * SS + kv0 + tid] ? 0.f : -1e30f;
    }
    __syncthreads();

    // QK^T
    f32x4 sc[2][4];
#pragma unroll
    for (int mq = 0; mq < 2; mq++)
#pragma unroll
      for (int ni = 0; ni < 4; ni++) sc[mq][ni] = (f32x4){0.f, 0.f, 0.f, 0.f};
#pragma unroll
    for (int kk = 0; kk < 2; kk++) {
      bf16x8 af[2], bf[4];
#pragma unroll
      for (int mq = 0; mq < 2; mq++)
        af[mq] = *reinterpret_cast<const bf16x8*>(&Qs[w * 32 + mq * 16 + lr][kk * 32 + lg * 8]);
#pragma unroll
      for (int ni = 0; ni < 4; ni++)
        bf[ni] = *reinterpret_cast<const bf16x8*>(&Ks[ni * 16 + lr][kk * 32 + lg * 8]);
#pragma unroll
      for (int mq = 0; mq < 2; mq++)
#pragma unroll
        for (int ni = 0; ni < 4; ni++)
          sc[mq][ni] = __builtin_amdgcn_mfma_f32_16x16x32_bf16(af[mq], bf[ni], sc[mq][ni], 0, 0, 0);
    }

    // online softmax
    float kmv[4];
#pragma unroll
    for (int ni = 0; ni < 4; ni++) kmv[ni] = km[ni * 16 + lr];
#pragma unroll
    for (int mq = 0; mq < 2; mq++) {
      int qrb = q0 + w * 32 + mq * 16 + lg * 4;
#pragma unroll
      for (int ni = 0; ni < 4; ni++) {
        int kg = kv0 + ni * 16 + lr;
#pragma unroll
        for (int j = 0; j < 4; j++) {
          float s = sc[mq][ni][j] + kmv[ni];
          sc[mq][ni][j] = (kg <= qrb + j) ? s : -1e30f;
        }
      }
      f32x4 rmax = sc[mq][0];
#pragma unroll
      for (int ni = 1; ni < 4; ni++)
#pragma unroll
        for (int j = 0; j < 4; j++) rmax[j] = fmaxf(rmax[j], sc[mq][ni][j]);
#pragma unroll
      for (int msk = 1; msk <= 8; msk <<= 1)
#pragma unroll
        for (int j = 0; j < 4; j++) rmax[j] = fmaxf(rmax[j], __shfl_xor(rmax[j], msk));
      f32x4 mnew, corr;
#pragma unroll
      for (int j = 0; j < 4; j++) {
        mnew[j] = fmaxf(m_run[mq][j], rmax[j]);
        corr[j] = __expf(m_run[mq][j] - mnew[j]);
      }
      m_run[mq] = mnew;
      f32x4 rs = (f32x4){0.f, 0.f, 0.f, 0.f};
#pragma unroll
      for (int ni = 0; ni < 4; ni++) {
#pragma unroll
        for (int j = 0; j < 4; j++) {
          float p = __expf(sc[mq][ni][j] - mnew[j]);
          rs[j] += p;
          Ps[w * 32 + mq * 16 + lg * 4 + j][ni * 16 + lr] = (bf16_t)p;
        }
      }
#pragma unroll
      for (int msk = 1; msk <= 8; msk <<= 1)
#pragma unroll
        for (int j = 0; j < 4; j++) rs[j] += __shfl_xor(rs[j], msk);
#pragma unroll
      for (int j = 0; j < 4; j++) l_run[mq][j] = l_run[mq][j] * corr[j] + rs[j];
#pragma unroll
      for (int nd = 0; nd < 4; nd++) o[mq][nd] = o[mq][nd] * corr;
    }

    // PV
#pragma unroll
    for (int kc = 0; kc < 2; kc++) {
      bf16x8 pa[2], vb[4];
#pragma unroll
      for (int mq = 0; mq < 2; mq++)
        pa[mq] = *reinterpret_cast<const bf16x8*>(&Ps[w * 32 + mq * 16 + lr][kc * 32 + lg * 8]);
#pragma unroll
      for (int nd = 0; nd < 4; nd++)
        vb[nd] = *reinterpret_cast<const bf16x8*>(&Vs[nd * 16 + lr][kc * 32 + lg * 8]);
#pragma unroll
      for (int mq = 0; mq < 2; mq++)
#pragma unroll
        for (int nd = 0; nd < 4; nd++)
          o[mq][nd] = __builtin_amdgcn_mfma_f32_16x16x32_bf16(pa[mq], vb[nd], o[mq][nd], 0, 0, 0);
    }
    __syncthreads();
  }

#pragma unroll
  for (int mq = 0; mq < 2; mq++) {
    f32x4 linv;
#pragma unroll
    for (int j = 0; j < 4; j++) linv[j] = 1.f / l_run[mq][j];
#pragma unroll
    for (int nd = 0; nd < 4; nd++)
#pragma unroll
      for (int j = 0; j < 4; j++) {
        int rowg = b * SS + q0 + w * 32 + mq * 16 + lg * 4 + j;
        int col = h * HD + nd * 16 + lr;
        ab[(size_t)rowg * EE + col] = (bf16_t)(o[mq][nd][j] * linv[j]);
      }
  }
}

extern "C" void kernel_launch(void* const* d_in, const int* in_sizes, int n_in,
                              void* d_out, int out_size, void* d_ws, size_t ws_size,
                              hipStream_t stream) {
  const int*   ids   = (const int*)d_in[0];
  const int*   amask = (const int*)d_in[1];
  const float* emb   = (const float*)d_in[2];
  const float* Wq    = (const float*)d_in[3];
  const float* Wk    = (const float*)d_in[4];
  const float* Wv    = (const float*)d_in[5];
  const float* Wo    = (const float*)d_in[6];
  const float* ln1g  = (const float*)d_in[7];
  const float* ln1b  = (const float*)d_in[8];
  const float* ln2g  = (const float*)d_in[9];
  const float* ln2b  = (const float*)d_in[10];
  const float* fw1   = (const float*)d_in[11];
  const float* fb1   = (const float*)d_in[12];
  const float* fw2   = (const float*)d_in[13];
  const float* fb2   = (const float*)d_in[14];
  const float* lnfg  = (const float*)d_in[15];
  const float* lnfb  = (const float*)d_in[16];
  const float* Wout  = (const float*)d_in[17];
  const float* bout  = (const float*)d_in[18];
  float* out = (float*)d_out;

  // ws: x (8MB) | xn (4MB) | WoutT (51.5MB padded to 50304 rows)
  float*  x     = (float*)d_ws;
  bf16_t* xn    = (bf16_t*)((char*)d_ws + (8u << 20));
  bf16_t* WoutT = (bf16_t*)((char*)d_ws + (12u << 20));
  // d_out head as scratch (57MB of 824MB; fully overwritten by final GEMM)
  char* sc = (char*)d_out;
  bf16_t* qbuf = (bf16_t*)(sc);
  bf16_t* kbuf = (bf16_t*)(sc + 4194304);
  bf16_t* vTb  = (bf16_t*)(sc + 8388608);
  bf16_t* ab   = (bf16_t*)(sc + 12582912);
  bf16_t* hb   = (bf16_t*)(sc + 16777216);
  bf16_t* Wqkv = (bf16_t*)(sc + 33554432);
  bf16_t* WoT  = (bf16_t*)(sc + 39845888);
  bf16_t* W1T  = (bf16_t*)(sc + 41943040);
  bf16_t* W2T  = (bf16_t*)(sc + 50331648);

  wconv_qkv_kernel<<<dim3(8, 1, 96), 256, 0, stream>>>(Wq, Wk, Wv, Wqkv);
  wconv_kernel<<<dim3(8, 8, LL), 256, 0, stream>>>(Wo, WoT, 512, 512, 512,
                                                   512L * 512, 512L * 512);
  wconv_kernel<<<dim3(8, 32, LL), 256, 0, stream>>>(fw1, W1T, 2048, 512, 2048,
                                                    512L * 2048, 2048L * 512);
  wconv_kernel<<<dim3(32, 8, LL), 256, 0, stream>>>(fw2, W2T, 512, 2048, 512,
                                                    2048L * 512, 512L * 2048);
  wconv_kernel<<<dim3(8, VPAD / 64, 1), 256, 0, stream>>>(Wout, WoutT, VV, 512, VV, 0, 0);

  embed_kernel<<<NTOK * EE / 256, 256, 0, stream>>>(ids, emb, x);

  for (int l = 0; l < LL; l++) {
    ln_kernel<<<NTOK / 4, 256, 0, stream>>>(x, xn, ln1g + l * EE, ln1b + l * EE);
    gemm_bf16<0, 64><<<dim3(12, 64), 256, 0, stream>>>(xn, Wqkv + (size_t)l * 1536 * 512,
        NTOK, 1536, 512, nullptr, nullptr, nullptr, qbuf, kbuf, vTb);
    attn_kernel<<<dim3(SS / QBLK, BB * HH), 256, 0, stream>>>(qbuf, kbuf, vTb, amask, ab);
    gemm_bf16<2, 64><<<dim3(4, 64), 256, 0, stream>>>(ab, WoT + (size_t)l * 512 * 512,
        NTOK, 512, 512, nullptr, x, nullptr, nullptr, nullptr, nullptr);
    ln_kernel<<<NTOK / 4, 256, 0, stream>>>(x, xn, ln2g + l * EE, ln2b + l * EE);
    gemm_bf16<1, 64><<<dim3(16, 64), 256, 0, stream>>>(xn, W1T + (size_t)l * 2048 * 512,
        NTOK, 2048, 512, fb1 + l * 2048, nullptr, hb, nullptr, nullptr, nullptr);
    gemm_bf16<2, 64><<<dim3(4, 64), 256, 0, stream>>>(hb, W2T + (size_t)l * 512 * 2048,
        NTOK, 512, 2048, fb2 + l * EE, x, nullptr, nullptr, nullptr, nullptr);
  }
  ln_kernel<<<NTOK / 4, 256, 0, stream>>>(x, xn, lnfg, lnfb);
  // B-resident vocab GEMM: one block per 128-col panel
  gemm_vocab<<<dim3(VPAD / 128), 512, 0, stream>>>(xn, WoutT, bout, out);
}

// Round 10
// 1731.167 us; speedup vs baseline: 1.0801x; 1.0801x over previous
//
#include <hip/hip_runtime.h>
#include <math.h>

#define BB 2
#define SS 2048
#define EE 512
#define HH 8
#define HD 64
#define LL 4
#define VV 50257
#define NTOK (BB*SS)
#define VPAD 50304   // 393 * 128

typedef __bf16 bf16_t;
typedef bf16_t bf16x8 __attribute__((ext_vector_type(8)));
typedef float  f32x4  __attribute__((ext_vector_type(4)));

__device__ __forceinline__ void gload_lds16(const void* g, void* l) {
  __builtin_amdgcn_global_load_lds(
      (const __attribute__((address_space(1))) void*)g,
      (__attribute__((address_space(3))) void*)l, 16, 0, 0);
}

// ---------------- embedding + sinusoidal PE ----------------
__global__ __launch_bounds__(256) void embed_kernel(const int* __restrict__ ids,
                                                    const float* __restrict__ emb,
                                                    float* __restrict__ x) {
  int idx = blockIdx.x * 256 + threadIdx.x;
  int e   = idx & (EE - 1);
  int tok = idx >> 9;
  int s   = tok & (SS - 1);
  int id  = ids[tok];
  float freq = expf((float)(e & ~1) * -0.01798894604f);
  float ang  = (float)s * freq;
  float pe   = (e & 1) ? cosf(ang) : sinf(ang);
  x[idx] = emb[(size_t)id * EE + e] + pe;
}

// ---------------- LayerNorm: fp32 in -> bf16 out, one wave per row ----------------
__global__ __launch_bounds__(256) void ln_kernel(const float* __restrict__ in,
                                                 bf16_t* __restrict__ out,
                                                 const float* __restrict__ g,
                                                 const float* __restrict__ b) {
  int wv = threadIdx.x >> 6, lane = threadIdx.x & 63;
  int row = blockIdx.x * 4 + wv;
  const float4* r = reinterpret_cast<const float4*>(in + (size_t)row * EE) + lane * 2;
  float4 v0 = r[0], v1 = r[1];
  float s = v0.x + v0.y + v0.z + v0.w + v1.x + v1.y + v1.z + v1.w;
#pragma unroll
  for (int o = 32; o > 0; o >>= 1) s += __shfl_xor(s, o);
  float mean = s * (1.f / EE);
  float d0 = v0.x-mean, d1 = v0.y-mean, d2 = v0.z-mean, d3 = v0.w-mean;
  float d4 = v1.x-mean, d5 = v1.y-mean, d6 = v1.z-mean, d7 = v1.w-mean;
  float var = d0*d0+d1*d1+d2*d2+d3*d3+d4*d4+d5*d5+d6*d6+d7*d7;
#pragma unroll
  for (int o = 32; o > 0; o >>= 1) var += __shfl_xor(var, o);
  float inv = rsqrtf(var * (1.f / EE) + 1e-5f);
  const float4* gp = reinterpret_cast<const float4*>(g) + lane * 2;
  const float4* bp = reinterpret_cast<const float4*>(b) + lane * 2;
  float4 g0 = gp[0], g1 = gp[1], b0 = bp[0], b1 = bp[1];
  bf16_t tmp[8];
  tmp[0] = (bf16_t)(d0*inv*g0.x + b0.x); tmp[1] = (bf16_t)(d1*inv*g0.y + b0.y);
  tmp[2] = (bf16_t)(d2*inv*g0.z + b0.z); tmp[3] = (bf16_t)(d3*inv*g0.w + b0.w);
  tmp[4] = (bf16_t)(d4*inv*g1.x + b1.x); tmp[5] = (bf16_t)(d5*inv*g1.y + b1.y);
  tmp[6] = (bf16_t)(d6*inv*g1.z + b1.z); tmp[7] = (bf16_t)(d7*inv*g1.w + b1.w);
  *reinterpret_cast<bf16x8*>(out + (size_t)row * EE + lane * 8) = *reinterpret_cast<bf16x8*>(tmp);
}

// ---------------- weight transpose+convert: fp32 [K][N] -> bf16 [N][K] ----------------
__device__ __forceinline__ void transpose_tile(const float* __restrict__ ip,
                                               bf16_t* __restrict__ op,
                                               int k0, int n0, int ldin, int ldout,
                                               int Nvalid, float* T) {
  int t = threadIdx.x;
  int r = t >> 2, cb = (t & 3) * 16;
#pragma unroll
  for (int i = 0; i < 16; i++) {
    int n = n0 + cb + i;
    T[r * 65 + cb + i] = (n < Nvalid) ? ip[(size_t)(k0 + r) * ldin + n] : 0.f;
  }
  __syncthreads();
  bf16_t tmp[16];
#pragma unroll
  for (int i = 0; i < 16; i++) tmp[i] = (bf16_t)T[(cb + i) * 65 + r];
  bf16_t* o = op + (size_t)(n0 + r) * ldout + k0 + cb;
  *reinterpret_cast<bf16x8*>(o)     = *reinterpret_cast<bf16x8*>(&tmp[0]);
  *reinterpret_cast<bf16x8*>(o + 8) = *reinterpret_cast<bf16x8*>(&tmp[8]);
}

__global__ __launch_bounds__(256) void wconv_kernel(const float* __restrict__ in,
                                                    bf16_t* __restrict__ out,
                                                    int ldin, int ldout, int Nvalid,
                                                    long zin, long zout) {
  __shared__ float T[64 * 65];
  transpose_tile(in + (size_t)blockIdx.z * zin, out + (size_t)blockIdx.z * zout,
                 blockIdx.x * 64, blockIdx.y * 64, ldin, ldout, Nvalid, T);
}

__global__ __launch_bounds__(256) void wconv_qkv_kernel(const float* __restrict__ Wq,
                                                        const float* __restrict__ Wk,
                                                        const float* __restrict__ Wv,
                                                        bf16_t* __restrict__ out) {
  __shared__ float T[64 * 65];
  int z = blockIdx.z;
  int l = z / 24, rem = z % 24, sec = rem >> 3, h = rem & 7;
  const float* W = sec == 0 ? Wq : (sec == 1 ? Wk : Wv);
  const float* ip = W + (size_t)(l * 8 + h) * (EE * HD);
  bf16_t* op = out + (size_t)l * (1536 * 512) + (size_t)(sec * 512 + h * 64) * 512;
  transpose_tile(ip, op, blockIdx.x * 64, 0, HD, EE, HD, T);
}

// ---------------- 64/128-tile bf16 MFMA GEMM (layer GEMMs), single-buffer ----
// Fragment-major LDS (0 conflicts).
// MODE: 0=QKV scatter, 1=bias+GELU->bf16, 2=(+bias)+residual f32.
template<int MODE, int TM>
__global__ __launch_bounds__(256) void gemm_bf16(
    const bf16_t* __restrict__ A, const bf16_t* __restrict__ Bt,
    int M, int N, int K,
    const float* __restrict__ bias,
    float* __restrict__ Cf, bf16_t* __restrict__ Cb,
    bf16_t* __restrict__ qo, bf16_t* __restrict__ ko, bf16_t* __restrict__ vo) {
  constexpr int MI = TM / 32;
  __shared__ __align__(16) bf16_t As[TM * 64];
  __shared__ __align__(16) bf16_t Bs[128 * 64];
  int tid = threadIdx.x, lane = tid & 63, w = tid >> 6;
  int lr = lane & 15, lg = lane >> 4;
  int m0 = blockIdx.y * TM, n0 = blockIdx.x * 128;
  f32x4 acc[MI][4];
#pragma unroll
  for (int i = 0; i < MI; i++)
#pragma unroll
    for (int j = 0; j < 4; j++) acc[i][j] = (f32x4){0.f, 0.f, 0.f, 0.f};
  int wr = w >> 1, wc = w & 1;

  const bf16_t* Abase = A  + (size_t)(m0 + lr) * K + lg * 8;
  const bf16_t* Bbase = Bt + (size_t)(n0 + lr) * K + lg * 8;

  for (int k0 = 0; k0 < K; k0 += 64) {
#pragma unroll
    for (int i = 0; i < MI; i++) {
      int c = w * MI + i;
      gload_lds16(Abase + (size_t)(c >> 1) * 16 * K + k0 + (c & 1) * 32,
                  (char*)As + c * 1024);
    }
#pragma unroll
    for (int i = 0; i < 4; i++) {
      int c = w * 4 + i;
      gload_lds16(Bbase + (size_t)(c >> 1) * 16 * K + k0 + (c & 1) * 32,
                  (char*)Bs + c * 1024);
    }
    __syncthreads();
#pragma unroll
    for (int kk = 0; kk < 2; kk++) {
      bf16x8 afr[MI], bfr[4];
#pragma unroll
      for (int mi = 0; mi < MI; mi++)
        afr[mi] = *reinterpret_cast<const bf16x8*>(
            &As[(((wr * MI + mi) << 1) + kk) * 512 + lane * 8]);
#pragma unroll
      for (int ni = 0; ni < 4; ni++)
        bfr[ni] = *reinterpret_cast<const bf16x8*>(
            &Bs[(((wc * 4 + ni) << 1) + kk) * 512 + lane * 8]);
#pragma unroll
      for (int mi = 0; mi < MI; mi++)
#pragma unroll
        for (int ni = 0; ni < 4; ni++)
          acc[mi][ni] = __builtin_amdgcn_mfma_f32_16x16x32_bf16(afr[mi], bfr[ni], acc[mi][ni], 0, 0, 0);
    }
    __syncthreads();
  }

#pragma unroll
  for (int mi = 0; mi < MI; mi++)
#pragma unroll
    for (int ni = 0; ni < 4; ni++) {
      int colg = n0 + wc * 64 + ni * 16 + lr;
#pragma unroll
      for (int j = 0; j < 4; j++) {
        int rowg = m0 + wr * (TM / 2) + mi * 16 + lg * 4 + j;
        float v = acc[mi][ni][j];
        if (MODE == 0) {
          int sec = colg >> 9, cc = colg & 511, hh = cc >> 6, dd = cc & 63;
          int bi = rowg >> 11, s = rowg & 2047;
          if (sec == 0)      qo[(((size_t)bi * HH + hh) * SS + s) * HD + dd] = (bf16_t)(v * 0.125f);
          else if (sec == 1) ko[(((size_t)bi * HH + hh) * SS + s) * HD + dd] = (bf16_t)v;
          else               vo[(((size_t)bi * HH + hh) * HD + dd) * SS + s] = (bf16_t)v;
        } else if (MODE == 1) {
          v += bias[colg];
          v = 0.5f * v * (1.f + erff(v * 0.70710678f));
          Cb[(size_t)rowg * N + colg] = (bf16_t)v;
        } else {
          if (bias) v += bias[colg];
          Cf[(size_t)rowg * EE + colg] += v;
        }
      }
    }
}

// ---------------- vocab GEMM "flat-B" (AITER flatmm style): ------------------
// A [4096][512] bf16 staged via LDS dbuf (32KB -> >=2 blocks/CU); B [VPAD][512]
// bf16 loaded global->VGPR per fragment (per-lane addr == staging addr, layout
// unchanged), depth-1 register prefetch. Raw s_barrier + counted vmcnt(8): A
// lands, B stays in flight. Grid N-fastest (write locality, r8-proven).
__global__ __launch_bounds__(256) void gemm_vocab(
    const bf16_t* __restrict__ A, const bf16_t* __restrict__ Bt,
    const float* __restrict__ bias, float* __restrict__ C) {
  __shared__ __align__(16) bf16_t As[2][128 * 64];
  int tid = threadIdx.x, lane = tid & 63, w = tid >> 6;
  int lr = lane & 15, lg = lane >> 4;
  int n0 = blockIdx.x * 128, m0 = blockIdx.y * 128;
  int wr = w >> 1, wc = w & 1;
  f32x4 acc[4][4];
#pragma unroll
  for (int i = 0; i < 4; i++)
#pragma unroll
    for (int j = 0; j < 4; j++) acc[i][j] = (f32x4){0.f, 0.f, 0.f, 0.f};

  const bf16_t* Abase = A  + (size_t)(m0 + lr) * 512 + lg * 8;
  const bf16_t* Bb    = Bt + (size_t)(n0 + wc * 64 + lr) * 512 + lg * 8;

  auto stageA = [&](int buf, int k0) {
#pragma unroll
    for (int i = 0; i < 4; i++) {
      int c = w * 4 + i;
      gload_lds16(Abase + (size_t)(c >> 1) * 16 * 512 + k0 + (c & 1) * 32,
                  (char*)&As[buf][0] + c * 1024);
    }
  };
  auto loadB = [&](bf16x8* dst, int k0) {
#pragma unroll
    for (int ni = 0; ni < 4; ni++)
#pragma unroll
      for (int kk = 0; kk < 2; kk++)
        dst[ni * 2 + kk] = *reinterpret_cast<const bf16x8*>(
            Bb + (size_t)ni * 16 * 512 + k0 + kk * 32);
  };

  bf16x8 bA[8], bB[8];
  stageA(0, 0);
  loadB(bA, 0);
  asm volatile("s_waitcnt vmcnt(0)" ::: "memory");
  __builtin_amdgcn_s_barrier();

#pragma unroll
  for (int t = 0; t < 8; t++) {
    int cur = t & 1;
    bf16x8* bc = (t & 1) ? bB : bA;   // static under full unroll
    bf16x8* bn = (t & 1) ? bA : bB;
    if (t < 7) {
      stageA(cur ^ 1, (t + 1) << 6);  // issued FIRST -> oldest in vmcnt queue
      loadB(bn, (t + 1) << 6);
    }
    bf16x8 afr[4][2];
#pragma unroll
    for (int mi = 0; mi < 4; mi++)
#pragma unroll
      for (int kk = 0; kk < 2; kk++)
        afr[mi][kk] = *reinterpret_cast<const bf16x8*>(
            &As[cur][(((wr * 4 + mi) << 1) + kk) * 512 + lane * 8]);
    asm volatile("s_waitcnt lgkmcnt(0)" ::: "memory");
    __builtin_amdgcn_sched_barrier(0);
    __builtin_amdgcn_s_setprio(1);
#pragma unroll
    for (int mi = 0; mi < 4; mi++)
#pragma unroll
      for (int ni = 0; ni < 4; ni++)
#pragma unroll
        for (int kk = 0; kk < 2; kk++)
          acc[mi][ni] = __builtin_amdgcn_mfma_f32_16x16x32_bf16(
              afr[mi][kk], bc[ni * 2 + kk], acc[mi][ni], 0, 0, 0);
    __builtin_amdgcn_s_setprio(0);
    if (t < 7) {
      // A(t+1)'s 4 gloads are the oldest of the 12 outstanding -> vmcnt(8)
      // retires exactly them; B(t+1) stays in flight (compiler waits on its
      // regs only when consumed next iter).
      asm volatile("s_waitcnt vmcnt(8)" ::: "memory");
      __builtin_amdgcn_s_barrier();
    }
  }

#pragma unroll
  for (int mi = 0; mi < 4; mi++)
#pragma unroll
    for (int ni = 0; ni < 4; ni++) {
      int colg = n0 + wc * 64 + ni * 16 + lr;
      if (colg < VV) {
        float bs = bias[colg];
#pragma unroll
        for (int j = 0; j < 4; j++) {
          int rowg = m0 + wr * 64 + mi * 16 + lg * 4 + j;
          C[(size_t)rowg * VV + colg] = acc[mi][ni][j] + bs;
        }
      }
    }
}

// ---------------- flash attention: QBLK=128 q-rows/block, KVB=64 tiles ----------------
#define QBLK 128
#define KVB 64
__global__ __launch_bounds__(256) void attn_kernel(
    const bf16_t* __restrict__ qb,   // [B,H,S,D], pre-scaled by 1/8
    const bf16_t* __restrict__ kb,   // [B,H,S,D]
    const bf16_t* __restrict__ vT,   // [B,H,D,S]
    const int* __restrict__ amask,   // [B,S]
    bf16_t* __restrict__ ab) {       // [B*S][E]
  __shared__ bf16_t Qs[QBLK][72];
  __shared__ bf16_t Ks[KVB][72];
  __shared__ bf16_t Vs[HD][72];
  __shared__ bf16_t Ps[QBLK][72];
  __shared__ float  km[KVB];
  int tid = threadIdx.x, lane = tid & 63, w = tid >> 6;
  int lr = lane & 15, lg = lane >> 4;
  int q0 = blockIdx.x * QBLK, bh = blockIdx.y, b = bh >> 3, h = bh & 7;
  const bf16_t* Qg = qb + (size_t)bh * SS * HD;
  const bf16_t* Kg = kb + (size_t)bh * SS * HD;
  const bf16_t* Vg = vT + (size_t)bh * HD * SS;

  { // stage Q tile
    int r = tid >> 1, c = (tid & 1) * 32;
    const uint4* s = reinterpret_cast<const uint4*>(Qg + (size_t)(q0 + r) * HD + c);
    uint4 a0 = s[0], a1 = s[1], a2 = s[2], a3 = s[3];
    *reinterpret_cast<uint4*>(&Qs[r][c])      = a0;
    *reinterpret_cast<uint4*>(&Qs[r][c + 8])  = a1;
    *reinterpret_cast<uint4*>(&Qs[r][c + 16]) = a2;
    *reinterpret_cast<uint4*>(&Qs[r][c + 24]) = a3;
  }

  f32x4 o[2][4];
  f32x4 m_run[2], l_run[2];
#pragma unroll
  for (int mq = 0; mq < 2; mq++) {
    m_run[mq] = (f32x4){-1e30f, -1e30f, -1e30f, -1e30f};
    l_run[mq] = (f32x4){0.f, 0.f, 0.f, 0.f};
#pragma unroll
    for (int nd = 0; nd < 4; nd++) o[mq][nd] = (f32x4){0.f, 0.f, 0.f, 0.f};
  }

  int ntile = (q0 >> 6) + 2;
  for (int t = 0; t < ntile; t++) {
    int kv0 = t * KVB;
    { // stage K, V^T, mask
      int r = tid >> 2, c = (tid & 3) * 16;
      const uint4* s = reinterpret_cast<const uint4*>(Kg + (size_t)(kv0 + r) * HD + c);
      uint4 x0 = s[0], x1 = s[1];
      *reinterpret_cast<uint4*>(&Ks[r][c])     = x0;
      *reinterpret_cast<uint4*>(&Ks[r][c + 8]) = x1;
      const uint4* sv = reinterpret_cast<const uint4*>(Vg + (size_t)r * SS + kv0 + c);
      uint4 y0 = sv[0], y1 = sv[1];
      *reinterpret_cast<uint4*>(&Vs[r][c])     = y0;
      *reinterpret_cast<uint4*>(&Vs[r][c + 8]) = y1;
      if (tid < KVB) km[tid] = amask[b * SS + kv0 + tid] ? 0.f : -1e30f;
    }
    __syncthreads();

    // QK^T
    f32x4 sc[2][4];
#pragma unroll
    for (int mq = 0; mq < 2; mq++)
#pragma unroll
      for (int ni = 0; ni < 4; ni++) sc[mq][ni] = (f32x4){0.f, 0.f, 0.f, 0.f};
#pragma unroll
    for (int kk = 0; kk < 2; kk++) {
      bf16x8 af[2], bf[4];
#pragma unroll
      for (int mq = 0; mq < 2; mq++)
        af[mq] = *reinterpret_cast<const bf16x8*>(&Qs[w * 32 + mq * 16 + lr][kk * 32 + lg * 8]);
#pragma unroll
      for (int ni = 0; ni < 4; ni++)
        bf[ni] = *reinterpret_cast<const bf16x8*>(&Ks[ni * 16 + lr][kk * 32 + lg * 8]);
#pragma unroll
      for (int mq = 0; mq < 2; mq++)
#pragma unroll
        for (int ni = 0; ni < 4; ni++)
          sc[mq][ni] = __builtin_amdgcn_mfma_f32_16x16x32_bf16(af[mq], bf[ni], sc[mq][ni], 0, 0, 0);
    }

    // online softmax
    float kmv[4];
#pragma unroll
    for (int ni = 0; ni < 4; ni++) kmv[ni] = km[ni * 16 + lr];
#pragma unroll
    for (int mq = 0; mq < 2; mq++) {
      int qrb = q0 + w * 32 + mq * 16 + lg * 4;
#pragma unroll
      for (int ni = 0; ni < 4; ni++) {
        int kg = kv0 + ni * 16 + lr;
#pragma unroll
        for (int j = 0; j < 4; j++) {
          float s = sc[mq][ni][j] + kmv[ni];
          sc[mq][ni][j] = (kg <= qrb + j) ? s : -1e30f;
        }
      }
      f32x4 rmax = sc[mq][0];
#pragma unroll
      for (int ni = 1; ni < 4; ni++)
#pragma unroll
        for (int j = 0; j < 4; j++) rmax[j] = fmaxf(rmax[j], sc[mq][ni][j]);
#pragma unroll
      for (int msk = 1; msk <= 8; msk <<= 1)
#pragma unroll
        for (int j = 0; j < 4; j++) rmax[j] = fmaxf(rmax[j], __shfl_xor(rmax[j], msk));
      f32x4 mnew, corr;
#pragma unroll
      for (int j = 0; j < 4; j++) {
        mnew[j] = fmaxf(m_run[mq][j], rmax[j]);
        corr[j] = __expf(m_run[mq][j] - mnew[j]);
      }
      m_run[mq] = mnew;
      f32x4 rs = (f32x4){0.f, 0.f, 0.f, 0.f};
#pragma unroll
      for (int ni = 0; ni < 4; ni++) {
#pragma unroll
        for (int j = 0; j < 4; j++) {
          float p = __expf(sc[mq][ni][j] - mnew[j]);
          rs[j] += p;
          Ps[w * 32 + mq * 16 + lg * 4 + j][ni * 16 + lr] = (bf16_t)p;
        }
      }
#pragma unroll
      for (int msk = 1; msk <= 8; msk <<= 1)
#pragma unroll
        for (int j = 0; j < 4; j++) rs[j] += __shfl_xor(rs[j], msk);
#pragma unroll
      for (int j = 0; j < 4; j++) l_run[mq][j] = l_run[mq][j] * corr[j] + rs[j];
#pragma unroll
      for (int nd = 0; nd < 4; nd++) o[mq][nd] = o[mq][nd] * corr;
    }

    // PV
#pragma unroll
    for (int kc = 0; kc < 2; kc++) {
      bf16x8 pa[2], vb[4];
#pragma unroll
      for (int mq = 0; mq < 2; mq++)
        pa[mq] = *reinterpret_cast<const bf16x8*>(&Ps[w * 32 + mq * 16 + lr][kc * 32 + lg * 8]);
#pragma unroll
      for (int nd = 0; nd < 4; nd++)
        vb[nd] = *reinterpret_cast<const bf16x8*>(&Vs[nd * 16 + lr][kc * 32 + lg * 8]);
#pragma unroll
      for (int mq = 0; mq < 2; mq++)
#pragma unroll
        for (int nd = 0; nd < 4; nd++)
          o[mq][nd] = __builtin_amdgcn_mfma_f32_16x16x32_bf16(pa[mq], vb[nd], o[mq][nd], 0, 0, 0);
    }
    __syncthreads();
  }

#pragma unroll
  for (int mq = 0; mq < 2; mq++) {
    f32x4 linv;
#pragma unroll
    for (int j = 0; j < 4; j++) linv[j] = 1.f / l_run[mq][j];
#pragma unroll
    for (int nd = 0; nd < 4; nd++)
#pragma unroll
      for (int j = 0; j < 4; j++) {
        int rowg = b * SS + q0 + w * 32 + mq * 16 + lg * 4 + j;
        int col = h * HD + nd * 16 + lr;
        ab[(size_t)rowg * EE + col] = (bf16_t)(o[mq][nd][j] * linv[j]);
      }
  }
}

extern "C" void kernel_launch(void* const* d_in, const int* in_sizes, int n_in,
                              void* d_out, int out_size, void* d_ws, size_t ws_size,
                              hipStream_t stream) {
  const int*   ids   = (const int*)d_in[0];
  const int*   amask = (const int*)d_in[1];
  const float* emb   = (const float*)d_in[2];
  const float* Wq    = (const float*)d_in[3];
  const float* Wk    = (const float*)d_in[4];
  const float* Wv    = (const float*)d_in[5];
  const float* Wo    = (const float*)d_in[6];
  const float* ln1g  = (const float*)d_in[7];
  const float* ln1b  = (const float*)d_in[8];
  const float* ln2g  = (const float*)d_in[9];
  const float* ln2b  = (const float*)d_in[10];
  const float* fw1   = (const float*)d_in[11];
  const float* fb1   = (const float*)d_in[12];
  const float* fw2   = (const float*)d_in[13];
  const float* fb2   = (const float*)d_in[14];
  const float* lnfg  = (const float*)d_in[15];
  const float* lnfb  = (const float*)d_in[16];
  const float* Wout  = (const float*)d_in[17];
  const float* bout  = (const float*)d_in[18];
  float* out = (float*)d_out;

  // ws: x (8MB) | xn (4MB) | WoutT (51.5MB padded to 50304 rows)
  float*  x     = (float*)d_ws;
  bf16_t* xn    = (bf16_t*)((char*)d_ws + (8u << 20));
  bf16_t* WoutT = (bf16_t*)((char*)d_ws + (12u << 20));
  // d_out head as scratch (57MB of 824MB; fully overwritten by final GEMM)
  char* sc = (char*)d_out;
  bf16_t* qbuf = (bf16_t*)(sc);
  bf16_t* kbuf = (bf16_t*)(sc + 4194304);
  bf16_t* vTb  = (bf16_t*)(sc + 8388608);
  bf16_t* ab   = (bf16_t*)(sc + 12582912);
  bf16_t* hb   = (bf16_t*)(sc + 16777216);
  bf16_t* Wqkv = (bf16_t*)(sc + 33554432);
  bf16_t* WoT  = (bf16_t*)(sc + 39845888);
  bf16_t* W1T  = (bf16_t*)(sc + 41943040);
  bf16_t* W2T  = (bf16_t*)(sc + 50331648);

  wconv_qkv_kernel<<<dim3(8, 1, 96), 256, 0, stream>>>(Wq, Wk, Wv, Wqkv);
  wconv_kernel<<<dim3(8, 8, LL), 256, 0, stream>>>(Wo, WoT, 512, 512, 512,
                                                   512L * 512, 512L * 512);
  wconv_kernel<<<dim3(8, 32, LL), 256, 0, stream>>>(fw1, W1T, 2048, 512, 2048,
                                                    512L * 2048, 2048L * 512);
  wconv_kernel<<<dim3(32, 8, LL), 256, 0, stream>>>(fw2, W2T, 512, 2048, 512,
                                                    2048L * 512, 512L * 2048);
  wconv_kernel<<<dim3(8, VPAD / 64, 1), 256, 0, stream>>>(Wout, WoutT, VV, 512, VV, 0, 0);

  embed_kernel<<<NTOK * EE / 256, 256, 0, stream>>>(ids, emb, x);

  for (int l = 0; l < LL; l++) {
    ln_kernel<<<NTOK / 4, 256, 0, stream>>>(x, xn, ln1g + l * EE, ln1b + l * EE);
    gemm_bf16<0, 128><<<dim3(12, 32), 256, 0, stream>>>(xn, Wqkv + (size_t)l * 1536 * 512,
        NTOK, 1536, 512, nullptr, nullptr, nullptr, qbuf, kbuf, vTb);
    attn_kernel<<<dim3(SS / QBLK, BB * HH), 256, 0, stream>>>(qbuf, kbuf, vTb, amask, ab);
    gemm_bf16<2, 64><<<dim3(4, 64), 256, 0, stream>>>(ab, WoT + (size_t)l * 512 * 512,
        NTOK, 512, 512, nullptr, x, nullptr, nullptr, nullptr, nullptr);
    ln_kernel<<<NTOK / 4, 256, 0, stream>>>(x, xn, ln2g + l * EE, ln2b + l * EE);
    gemm_bf16<1, 128><<<dim3(16, 32), 256, 0, stream>>>(xn, W1T + (size_t)l * 2048 * 512,
        NTOK, 2048, 512, fb1 + l * 2048, nullptr, hb, nullptr, nullptr, nullptr);
    gemm_bf16<2, 64><<<dim3(4, 64), 256, 0, stream>>>(hb, W2T + (size_t)l * 512 * 2048,
        NTOK, 512, 2048, fb2 + l * EE, x, nullptr, nullptr, nullptr, nullptr);
  }
  ln_kernel<<<NTOK / 4, 256, 0, stream>>>(x, xn, lnfg, lnfb);
  // flat-B vocab GEMM, N-fastest grid (write locality)
  gemm_vocab<<<dim3(VPAD / 128, 32), 256, 0, stream>>>(xn, WoutT, bout, out);
}

// Round 11
// 1513.194 us; speedup vs baseline: 1.2357x; 1.1440x over previous
//
#include <hip/hip_runtime.h>
#include <math.h>

#define BB 2
#define SS 2048
#define EE 512
#define HH 8
#define HD 64
#define LL 4
#define VV 50257
#define NTOK (BB*SS)
#define VPAD2 50432   // 197 * 256

typedef __bf16 bf16_t;
typedef bf16_t bf16x8 __attribute__((ext_vector_type(8)));
typedef float  f32x4  __attribute__((ext_vector_type(4)));

__device__ __forceinline__ void gload_lds16(const void* g, void* l) {
  __builtin_amdgcn_global_load_lds(
      (const __attribute__((address_space(1))) void*)g,
      (__attribute__((address_space(3))) void*)l, 16, 0, 0);
}

// ---------------- embedding + sinusoidal PE ----------------
__global__ __launch_bounds__(256) void embed_kernel(const int* __restrict__ ids,
                                                    const float* __restrict__ emb,
                                                    float* __restrict__ x) {
  int idx = blockIdx.x * 256 + threadIdx.x;
  int e   = idx & (EE - 1);
  int tok = idx >> 9;
  int s   = tok & (SS - 1);
  int id  = ids[tok];
  float freq = expf((float)(e & ~1) * -0.01798894604f);
  float ang  = (float)s * freq;
  float pe   = (e & 1) ? cosf(ang) : sinf(ang);
  x[idx] = emb[(size_t)id * EE + e] + pe;
}

// ---------------- LayerNorm: fp32 in -> bf16 out, one wave per row ----------------
__global__ __launch_bounds__(256) void ln_kernel(const float* __restrict__ in,
                                                 bf16_t* __restrict__ out,
                                                 const float* __restrict__ g,
                                                 const float* __restrict__ b) {
  int wv = threadIdx.x >> 6, lane = threadIdx.x & 63;
  int row = blockIdx.x * 4 + wv;
  const float4* r = reinterpret_cast<const float4*>(in + (size_t)row * EE) + lane * 2;
  float4 v0 = r[0], v1 = r[1];
  float s = v0.x + v0.y + v0.z + v0.w + v1.x + v1.y + v1.z + v1.w;
#pragma unroll
  for (int o = 32; o > 0; o >>= 1) s += __shfl_xor(s, o);
  float mean = s * (1.f / EE);
  float d0 = v0.x-mean, d1 = v0.y-mean, d2 = v0.z-mean, d3 = v0.w-mean;
  float d4 = v1.x-mean, d5 = v1.y-mean, d6 = v1.z-mean, d7 = v1.w-mean;
  float var = d0*d0+d1*d1+d2*d2+d3*d3+d4*d4+d5*d5+d6*d6+d7*d7;
#pragma unroll
  for (int o = 32; o > 0; o >>= 1) var += __shfl_xor(var, o);
  float inv = rsqrtf(var * (1.f / EE) + 1e-5f);
  const float4* gp = reinterpret_cast<const float4*>(g) + lane * 2;
  const float4* bp = reinterpret_cast<const float4*>(b) + lane * 2;
  float4 g0 = gp[0], g1 = gp[1], b0 = bp[0], b1 = bp[1];
  bf16_t tmp[8];
  tmp[0] = (bf16_t)(d0*inv*g0.x + b0.x); tmp[1] = (bf16_t)(d1*inv*g0.y + b0.y);
  tmp[2] = (bf16_t)(d2*inv*g0.z + b0.z); tmp[3] = (bf16_t)(d3*inv*g0.w + b0.w);
  tmp[4] = (bf16_t)(d4*inv*g1.x + b1.x); tmp[5] = (bf16_t)(d5*inv*g1.y + b1.y);
  tmp[6] = (bf16_t)(d6*inv*g1.z + b1.z); tmp[7] = (bf16_t)(d7*inv*g1.w + b1.w);
  *reinterpret_cast<bf16x8*>(out + (size_t)row * EE + lane * 8) = *reinterpret_cast<bf16x8*>(tmp);
}

// ---------------- weight transpose+convert: fp32 [K][N] -> bf16 [N][K] ----------------
__device__ __forceinline__ void transpose_tile(const float* __restrict__ ip,
                                               bf16_t* __restrict__ op,
                                               int k0, int n0, int ldin, int ldout,
                                               int Nvalid, float* T) {
  int t = threadIdx.x;
  int r = t >> 2, cb = (t & 3) * 16;
#pragma unroll
  for (int i = 0; i < 16; i++) {
    int n = n0 + cb + i;
    T[r * 65 + cb + i] = (n < Nvalid) ? ip[(size_t)(k0 + r) * ldin + n] : 0.f;
  }
  __syncthreads();
  bf16_t tmp[16];
#pragma unroll
  for (int i = 0; i < 16; i++) tmp[i] = (bf16_t)T[(cb + i) * 65 + r];
  bf16_t* o = op + (size_t)(n0 + r) * ldout + k0 + cb;
  *reinterpret_cast<bf16x8*>(o)     = *reinterpret_cast<bf16x8*>(&tmp[0]);
  *reinterpret_cast<bf16x8*>(o + 8) = *reinterpret_cast<bf16x8*>(&tmp[8]);
}

__global__ __launch_bounds__(256) void wconv_kernel(const float* __restrict__ in,
                                                    bf16_t* __restrict__ out,
                                                    int ldin, int ldout, int Nvalid,
                                                    long zin, long zout) {
  __shared__ float T[64 * 65];
  transpose_tile(in + (size_t)blockIdx.z * zin, out + (size_t)blockIdx.z * zout,
                 blockIdx.x * 64, blockIdx.y * 64, ldin, ldout, Nvalid, T);
}

__global__ __launch_bounds__(256) void wconv_qkv_kernel(const float* __restrict__ Wq,
                                                        const float* __restrict__ Wk,
                                                        const float* __restrict__ Wv,
                                                        bf16_t* __restrict__ out) {
  __shared__ float T[64 * 65];
  int z = blockIdx.z;
  int l = z / 24, rem = z % 24, sec = rem >> 3, h = rem & 7;
  const float* W = sec == 0 ? Wq : (sec == 1 ? Wk : Wv);
  const float* ip = W + (size_t)(l * 8 + h) * (EE * HD);
  bf16_t* op = out + (size_t)l * (1536 * 512) + (size_t)(sec * 512 + h * 64) * 512;
  transpose_tile(ip, op, blockIdx.x * 64, 0, HD, EE, HD, T);
}

// ---------------- 64/128-tile bf16 MFMA GEMM (layer GEMMs), single-buffer ----
// Fragment-major LDS (0 conflicts).
// MODE: 0=QKV scatter, 1=bias+GELU->bf16, 2=(+bias)+residual f32.
template<int MODE, int TM>
__global__ __launch_bounds__(256) void gemm_bf16(
    const bf16_t* __restrict__ A, const bf16_t* __restrict__ Bt,
    int M, int N, int K,
    const float* __restrict__ bias,
    float* __restrict__ Cf, bf16_t* __restrict__ Cb,
    bf16_t* __restrict__ qo, bf16_t* __restrict__ ko, bf16_t* __restrict__ vo) {
  constexpr int MI = TM / 32;
  __shared__ __align__(16) bf16_t As[TM * 64];
  __shared__ __align__(16) bf16_t Bs[128 * 64];
  int tid = threadIdx.x, lane = tid & 63, w = tid >> 6;
  int lr = lane & 15, lg = lane >> 4;
  int m0 = blockIdx.y * TM, n0 = blockIdx.x * 128;
  f32x4 acc[MI][4];
#pragma unroll
  for (int i = 0; i < MI; i++)
#pragma unroll
    for (int j = 0; j < 4; j++) acc[i][j] = (f32x4){0.f, 0.f, 0.f, 0.f};
  int wr = w >> 1, wc = w & 1;

  const bf16_t* Abase = A  + (size_t)(m0 + lr) * K + lg * 8;
  const bf16_t* Bbase = Bt + (size_t)(n0 + lr) * K + lg * 8;

  for (int k0 = 0; k0 < K; k0 += 64) {
#pragma unroll
    for (int i = 0; i < MI; i++) {
      int c = w * MI + i;
      gload_lds16(Abase + (size_t)(c >> 1) * 16 * K + k0 + (c & 1) * 32,
                  (char*)As + c * 1024);
    }
#pragma unroll
    for (int i = 0; i < 4; i++) {
      int c = w * 4 + i;
      gload_lds16(Bbase + (size_t)(c >> 1) * 16 * K + k0 + (c & 1) * 32,
                  (char*)Bs + c * 1024);
    }
    __syncthreads();
#pragma unroll
    for (int kk = 0; kk < 2; kk++) {
      bf16x8 afr[MI], bfr[4];
#pragma unroll
      for (int mi = 0; mi < MI; mi++)
        afr[mi] = *reinterpret_cast<const bf16x8*>(
            &As[(((wr * MI + mi) << 1) + kk) * 512 + lane * 8]);
#pragma unroll
      for (int ni = 0; ni < 4; ni++)
        bfr[ni] = *reinterpret_cast<const bf16x8*>(
            &Bs[(((wc * 4 + ni) << 1) + kk) * 512 + lane * 8]);
#pragma unroll
      for (int mi = 0; mi < MI; mi++)
#pragma unroll
        for (int ni = 0; ni < 4; ni++)
          acc[mi][ni] = __builtin_amdgcn_mfma_f32_16x16x32_bf16(afr[mi], bfr[ni], acc[mi][ni], 0, 0, 0);
    }
    __syncthreads();
  }

#pragma unroll
  for (int mi = 0; mi < MI; mi++)
#pragma unroll
    for (int ni = 0; ni < 4; ni++) {
      int colg = n0 + wc * 64 + ni * 16 + lr;
#pragma unroll
      for (int j = 0; j < 4; j++) {
        int rowg = m0 + wr * (TM / 2) + mi * 16 + lg * 4 + j;
        float v = acc[mi][ni][j];
        if (MODE == 0) {
          int sec = colg >> 9, cc = colg & 511, hh = cc >> 6, dd = cc & 63;
          int bi = rowg >> 11, s = rowg & 2047;
          if (sec == 0)      qo[(((size_t)bi * HH + hh) * SS + s) * HD + dd] = (bf16_t)(v * 0.125f);
          else if (sec == 1) ko[(((size_t)bi * HH + hh) * SS + s) * HD + dd] = (bf16_t)v;
          else               vo[(((size_t)bi * HH + hh) * HD + dd) * SS + s] = (bf16_t)v;
        } else if (MODE == 1) {
          v += bias[colg];
          v = 0.5f * v * (1.f + erff(v * 0.70710678f));
          Cb[(size_t)rowg * N + colg] = (bf16_t)v;
        } else {
          if (bias) v += bias[colg];
          Cf[(size_t)rowg * EE + colg] += v;
        }
      }
    }
}

// ---------------- vocab GEMM: r8's best (256², counted vmcnt, N-fastest) -----
__global__ __launch_bounds__(512) void gemm256_out(
    const bf16_t* __restrict__ A, const bf16_t* __restrict__ Bt,
    const float* __restrict__ bias, float* __restrict__ C) {
  __shared__ __align__(16) bf16_t As[2][256 * 64];
  __shared__ __align__(16) bf16_t Bs[2][256 * 64];
  int tid = threadIdx.x, lane = tid & 63, w = tid >> 6;
  int lr = lane & 15, lg = lane >> 4;
  int bid = blockIdx.x;
  int n0 = (bid % 197) * 256, m0 = (bid / 197) * 256;   // N-fastest (write locality)
  int wr = w >> 2, wc = w & 3;
  f32x4 acc[8][4];
#pragma unroll
  for (int i = 0; i < 8; i++)
#pragma unroll
    for (int j = 0; j < 4; j++) acc[i][j] = (f32x4){0.f, 0.f, 0.f, 0.f};

  const bf16_t* Abase = A  + (size_t)(m0 + lr) * 512 + lg * 8;
  const bf16_t* Bbase = Bt + (size_t)(n0 + lr) * 512 + lg * 8;

  auto stage = [&](int b, int k0) {
#pragma unroll
    for (int i = 0; i < 4; i++) {
      int c = w * 4 + i;
      gload_lds16(Abase + (size_t)(c >> 1) * 16 * 512 + k0 + (c & 1) * 32,
                  (char*)&As[b][0] + c * 1024);
      gload_lds16(Bbase + (size_t)(c >> 1) * 16 * 512 + k0 + (c & 1) * 32,
                  (char*)&Bs[b][0] + c * 1024);
    }
  };

  stage(0, 0);
  stage(1, 64);
  asm volatile("s_waitcnt vmcnt(8)" ::: "memory");
  asm volatile("s_barrier" ::: "memory");

  for (int t = 0; t < 8; ++t) {
    int b = t & 1;
    bf16x8 breg[4][2];
#pragma unroll
    for (int q = 0; q < 4; q++) {
      if (q == 0) {
#pragma unroll
        for (int ni = 0; ni < 4; ni++)
#pragma unroll
          for (int kk = 0; kk < 2; kk++)
            breg[ni][kk] = *reinterpret_cast<const bf16x8*>(
                &Bs[b][(((wc * 4 + ni) << 1) + kk) * 512 + lane * 8]);
      }
      bf16x8 areg[2][2];
#pragma unroll
      for (int u = 0; u < 2; u++)
#pragma unroll
        for (int kk = 0; kk < 2; kk++)
          areg[u][kk] = *reinterpret_cast<const bf16x8*>(
              &As[b][(((wr * 8 + 2 * q + u) << 1) + kk) * 512 + lane * 8]);
      asm volatile("s_waitcnt lgkmcnt(0)" ::: "memory");
      __builtin_amdgcn_sched_barrier(0);
      __builtin_amdgcn_s_setprio(1);
#pragma unroll
      for (int u = 0; u < 2; u++)
#pragma unroll
        for (int ni = 0; ni < 4; ni++)
#pragma unroll
          for (int kk = 0; kk < 2; kk++)
            acc[2 * q + u][ni] = __builtin_amdgcn_mfma_f32_16x16x32_bf16(
                areg[u][kk], breg[ni][kk], acc[2 * q + u][ni], 0, 0, 0);
      __builtin_amdgcn_s_setprio(0);
      asm volatile("s_barrier" ::: "memory");
    }
    if (t < 6) {
      stage(b, (t + 2) << 6);
      asm volatile("s_waitcnt vmcnt(8)" ::: "memory");
      asm volatile("s_barrier" ::: "memory");
    } else if (t == 6) {
      asm volatile("s_waitcnt vmcnt(0)" ::: "memory");
      asm volatile("s_barrier" ::: "memory");
    }
  }

#pragma unroll
  for (int mi = 0; mi < 8; mi++)
#pragma unroll
    for (int ni = 0; ni < 4; ni++) {
      int colg = n0 + wc * 64 + ni * 16 + lr;
      if (colg < VV) {
        float bs = bias[colg];
#pragma unroll
        for (int j = 0; j < 4; j++) {
          int rowg = m0 + wr * 128 + mi * 16 + lg * 4 + j;
          C[(size_t)rowg * VV + colg] = acc[mi][ni][j] + bs;
        }
      }
    }
}

// ---------------- flash attention v2: dbuf fragment-major K/V prefetch -------
// K/V tiles staged via global_load_lds into 2-buffer fragment-major LDS; tile
// t+1's 16 loads issued BEFORE computing tile t (T14 issue-early) -> ~900cyc
// load latency hides under ~1500cyc compute. One vmcnt(0)+s_barrier per tile.
#define QBLK 128
#define KVB 64
__global__ __launch_bounds__(256) void attn_kernel(
    const bf16_t* __restrict__ qb,   // [B,H,S,D], pre-scaled by 1/8
    const bf16_t* __restrict__ kb,   // [B,H,S,D]
    const bf16_t* __restrict__ vT,   // [B,H,D,S]
    const int* __restrict__ amask,   // [B,S]
    bf16_t* __restrict__ ab) {       // [B*S][E]
  __shared__ bf16_t Qs[QBLK][72];                    // 18 KB
  __shared__ bf16_t Ps[QBLK][72];                    // 18 KB
  __shared__ __align__(16) bf16_t Ks[2][KVB * 64];   // 16 KB
  __shared__ __align__(16) bf16_t Vs[2][KVB * 64];   // 16 KB
  __shared__ float kmAll[SS];                        // 8 KB  (total 76 KB)
  int tid = threadIdx.x, lane = tid & 63, w = tid >> 6;
  int lr = lane & 15, lg = lane >> 4;
  int q0 = blockIdx.x * QBLK, bh = blockIdx.y, b = bh >> 3, h = bh & 7;
  const bf16_t* Qg = qb + (size_t)bh * SS * HD;
  const bf16_t* Kg = kb + (size_t)bh * SS * HD;
  const bf16_t* Vg = vT + (size_t)bh * HD * SS;

  { // stage Q tile (vector loads -> LDS)
    int r = tid >> 1, c = (tid & 1) * 32;
    const uint4* s = reinterpret_cast<const uint4*>(Qg + (size_t)(q0 + r) * HD + c);
    uint4 a0 = s[0], a1 = s[1], a2 = s[2], a3 = s[3];
    *reinterpret_cast<uint4*>(&Qs[r][c])      = a0;
    *reinterpret_cast<uint4*>(&Qs[r][c + 8])  = a1;
    *reinterpret_cast<uint4*>(&Qs[r][c + 16]) = a2;
    *reinterpret_cast<uint4*>(&Qs[r][c + 24]) = a3;
  }
  // mask table once per block
#pragma unroll
  for (int i = 0; i < 8; i++) {
    int s = i * 256 + tid;
    kmAll[s] = amask[b * SS + s] ? 0.f : -1e30f;
  }

  // fragment-major K/V tile staging: 16 sub-blocks (8 K + 8 V), 4 per wave
  auto stageKV = [&](int buf, int kv0) {
#pragma unroll
    for (int i = 0; i < 4; i++) {
      int c = w * 4 + i;
      if (c < 8) {
        gload_lds16(Kg + (size_t)(kv0 + (c >> 1) * 16 + lr) * HD + (c & 1) * 32 + lg * 8,
                    (char*)&Ks[buf][0] + c * 1024);
      } else {
        int cc = c - 8;
        gload_lds16(Vg + (size_t)((cc >> 1) * 16 + lr) * SS + kv0 + (cc & 1) * 32 + lg * 8,
                    (char*)&Vs[buf][0] + cc * 1024);
      }
    }
  };

  f32x4 o[2][4];
  f32x4 m_run[2], l_run[2];
#pragma unroll
  for (int mq = 0; mq < 2; mq++) {
    m_run[mq] = (f32x4){-1e30f, -1e30f, -1e30f, -1e30f};
    l_run[mq] = (f32x4){0.f, 0.f, 0.f, 0.f};
#pragma unroll
    for (int nd = 0; nd < 4; nd++) o[mq][nd] = (f32x4){0.f, 0.f, 0.f, 0.f};
  }

  stageKV(0, 0);
  __syncthreads();   // drains vm+lgkm: Q, kmAll, and tile-0 K/V all visible

  int ntile = (q0 >> 6) + 2;
  for (int t = 0; t < ntile; t++) {
    int buf = t & 1;
    int kv0 = t * KVB;
    if (t + 1 < ntile) stageKV(buf ^ 1, kv0 + KVB);  // issue-early prefetch

    // QK^T from Ks[buf]
    f32x4 sc[2][4];
#pragma unroll
    for (int mq = 0; mq < 2; mq++)
#pragma unroll
      for (int ni = 0; ni < 4; ni++) sc[mq][ni] = (f32x4){0.f, 0.f, 0.f, 0.f};
#pragma unroll
    for (int kk = 0; kk < 2; kk++) {
      bf16x8 af[2], bf[4];
#pragma unroll
      for (int mq = 0; mq < 2; mq++)
        af[mq] = *reinterpret_cast<const bf16x8*>(&Qs[w * 32 + mq * 16 + lr][kk * 32 + lg * 8]);
#pragma unroll
      for (int ni = 0; ni < 4; ni++)
        bf[ni] = *reinterpret_cast<const bf16x8*>(&Ks[buf][(((ni << 1) + kk)) * 512 + lane * 8]);
#pragma unroll
      for (int mq = 0; mq < 2; mq++)
#pragma unroll
        for (int ni = 0; ni < 4; ni++)
          sc[mq][ni] = __builtin_amdgcn_mfma_f32_16x16x32_bf16(af[mq], bf[ni], sc[mq][ni], 0, 0, 0);
    }

    // online softmax
    float kmv[4];
#pragma unroll
    for (int ni = 0; ni < 4; ni++) kmv[ni] = kmAll[kv0 + ni * 16 + lr];
#pragma unroll
    for (int mq = 0; mq < 2; mq++) {
      int qrb = q0 + w * 32 + mq * 16 + lg * 4;
#pragma unroll
      for (int ni = 0; ni < 4; ni++) {
        int kg = kv0 + ni * 16 + lr;
#pragma unroll
        for (int j = 0; j < 4; j++) {
          float s = sc[mq][ni][j] + kmv[ni];
          sc[mq][ni][j] = (kg <= qrb + j) ? s : -1e30f;
        }
      }
      f32x4 rmax = sc[mq][0];
#pragma unroll
      for (int ni = 1; ni < 4; ni++)
#pragma unroll
        for (int j = 0; j < 4; j++) rmax[j] = fmaxf(rmax[j], sc[mq][ni][j]);
#pragma unroll
      for (int msk = 1; msk <= 8; msk <<= 1)
#pragma unroll
        for (int j = 0; j < 4; j++) rmax[j] = fmaxf(rmax[j], __shfl_xor(rmax[j], msk));
      f32x4 mnew, corr;
#pragma unroll
      for (int j = 0; j < 4; j++) {
        mnew[j] = fmaxf(m_run[mq][j], rmax[j]);
        corr[j] = __expf(m_run[mq][j] - mnew[j]);
      }
      m_run[mq] = mnew;
      f32x4 rs = (f32x4){0.f, 0.f, 0.f, 0.f};
#pragma unroll
      for (int ni = 0; ni < 4; ni++) {
#pragma unroll
        for (int j = 0; j < 4; j++) {
          float p = __expf(sc[mq][ni][j] - mnew[j]);
          rs[j] += p;
          Ps[w * 32 + mq * 16 + lg * 4 + j][ni * 16 + lr] = (bf16_t)p;
        }
      }
#pragma unroll
      for (int msk = 1; msk <= 8; msk <<= 1)
#pragma unroll
        for (int j = 0; j < 4; j++) rs[j] += __shfl_xor(rs[j], msk);
#pragma unroll
      for (int j = 0; j < 4; j++) l_run[mq][j] = l_run[mq][j] * corr[j] + rs[j];
#pragma unroll
      for (int nd = 0; nd < 4; nd++) o[mq][nd] = o[mq][nd] * corr;
    }

    // PV from Vs[buf] (Ps is per-wave private slice: no barrier needed)
#pragma unroll
    for (int kc = 0; kc < 2; kc++) {
      bf16x8 pa[2], vb[4];
#pragma unroll
      for (int mq = 0; mq < 2; mq++)
        pa[mq] = *reinterpret_cast<const bf16x8*>(&Ps[w * 32 + mq * 16 + lr][kc * 32 + lg * 8]);
#pragma unroll
      for (int nd = 0; nd < 4; nd++)
        vb[nd] = *reinterpret_cast<const bf16x8*>(&Vs[buf][(((nd << 1) + kc)) * 512 + lane * 8]);
#pragma unroll
      for (int mq = 0; mq < 2; mq++)
#pragma unroll
        for (int nd = 0; nd < 4; nd++)
          o[mq][nd] = __builtin_amdgcn_mfma_f32_16x16x32_bf16(pa[mq], vb[nd], o[mq][nd], 0, 0, 0);
    }
    // prefetched tile landed during compute; barrier closes the buffer handoff
    asm volatile("s_waitcnt vmcnt(0)" ::: "memory");
    asm volatile("s_barrier" ::: "memory");
  }

#pragma unroll
  for (int mq = 0; mq < 2; mq++) {
    f32x4 linv;
#pragma unroll
    for (int j = 0; j < 4; j++) linv[j] = 1.f / l_run[mq][j];
#pragma unroll
    for (int nd = 0; nd < 4; nd++)
#pragma unroll
      for (int j = 0; j < 4; j++) {
        int rowg = b * SS + q0 + w * 32 + mq * 16 + lg * 4 + j;
        int col = h * HD + nd * 16 + lr;
        ab[(size_t)rowg * EE + col] = (bf16_t)(o[mq][nd][j] * linv[j]);
      }
  }
}

extern "C" void kernel_launch(void* const* d_in, const int* in_sizes, int n_in,
                              void* d_out, int out_size, void* d_ws, size_t ws_size,
                              hipStream_t stream) {
  const int*   ids   = (const int*)d_in[0];
  const int*   amask = (const int*)d_in[1];
  const float* emb   = (const float*)d_in[2];
  const float* Wq    = (const float*)d_in[3];
  const float* Wk    = (const float*)d_in[4];
  const float* Wv    = (const float*)d_in[5];
  const float* Wo    = (const float*)d_in[6];
  const float* ln1g  = (const float*)d_in[7];
  const float* ln1b  = (const float*)d_in[8];
  const float* ln2g  = (const float*)d_in[9];
  const float* ln2b  = (const float*)d_in[10];
  const float* fw1   = (const float*)d_in[11];
  const float* fb1   = (const float*)d_in[12];
  const float* fw2   = (const float*)d_in[13];
  const float* fb2   = (const float*)d_in[14];
  const float* lnfg  = (const float*)d_in[15];
  const float* lnfb  = (const float*)d_in[16];
  const float* Wout  = (const float*)d_in[17];
  const float* bout  = (const float*)d_in[18];
  float* out = (float*)d_out;

  // ws: x (8MB) | xn (4MB) | WoutT (51.7MB padded to 50432 rows)
  float*  x     = (float*)d_ws;
  bf16_t* xn    = (bf16_t*)((char*)d_ws + (8u << 20));
  bf16_t* WoutT = (bf16_t*)((char*)d_ws + (12u << 20));
  // d_out head as scratch (57MB of 824MB; fully overwritten by final GEMM)
  char* sc = (char*)d_out;
  bf16_t* qbuf = (bf16_t*)(sc);
  bf16_t* kbuf = (bf16_t*)(sc + 4194304);
  bf16_t* vTb  = (bf16_t*)(sc + 8388608);
  bf16_t* ab   = (bf16_t*)(sc + 12582912);
  bf16_t* hb   = (bf16_t*)(sc + 16777216);
  bf16_t* Wqkv = (bf16_t*)(sc + 33554432);
  bf16_t* WoT  = (bf16_t*)(sc + 39845888);
  bf16_t* W1T  = (bf16_t*)(sc + 41943040);
  bf16_t* W2T  = (bf16_t*)(sc + 50331648);

  wconv_qkv_kernel<<<dim3(8, 1, 96), 256, 0, stream>>>(Wq, Wk, Wv, Wqkv);
  wconv_kernel<<<dim3(8, 8, LL), 256, 0, stream>>>(Wo, WoT, 512, 512, 512,
                                                   512L * 512, 512L * 512);
  wconv_kernel<<<dim3(8, 32, LL), 256, 0, stream>>>(fw1, W1T, 2048, 512, 2048,
                                                    512L * 2048, 2048L * 512);
  wconv_kernel<<<dim3(32, 8, LL), 256, 0, stream>>>(fw2, W2T, 512, 2048, 512,
                                                    2048L * 512, 512L * 2048);
  wconv_kernel<<<dim3(8, VPAD2 / 64, 1), 256, 0, stream>>>(Wout, WoutT, VV, 512, VV, 0, 0);

  embed_kernel<<<NTOK * EE / 256, 256, 0, stream>>>(ids, emb, x);

  for (int l = 0; l < LL; l++) {
    ln_kernel<<<NTOK / 4, 256, 0, stream>>>(x, xn, ln1g + l * EE, ln1b + l * EE);
    gemm_bf16<0, 128><<<dim3(12, 32), 256, 0, stream>>>(xn, Wqkv + (size_t)l * 1536 * 512,
        NTOK, 1536, 512, nullptr, nullptr, nullptr, qbuf, kbuf, vTb);
    attn_kernel<<<dim3(SS / QBLK, BB * HH), 256, 0, stream>>>(qbuf, kbuf, vTb, amask, ab);
    gemm_bf16<2, 64><<<dim3(4, 64), 256, 0, stream>>>(ab, WoT + (size_t)l * 512 * 512,
        NTOK, 512, 512, nullptr, x, nullptr, nullptr, nullptr, nullptr);
    ln_kernel<<<NTOK / 4, 256, 0, stream>>>(x, xn, ln2g + l * EE, ln2b + l * EE);
    gemm_bf16<1, 128><<<dim3(16, 32), 256, 0, stream>>>(xn, W1T + (size_t)l * 2048 * 512,
        NTOK, 2048, 512, fb1 + l * 2048, nullptr, hb, nullptr, nullptr, nullptr);
    gemm_bf16<2, 64><<<dim3(4, 64), 256, 0, stream>>>(hb, W2T + (size_t)l * 512 * 2048,
        NTOK, 512, 2048, fb2 + l * EE, x, nullptr, nullptr, nullptr, nullptr);
  }
  ln_kernel<<<NTOK / 4, 256, 0, stream>>>(x, xn, lnfg, lnfb);
  gemm256_out<<<dim3(16 * (VPAD2 / 256)), 512, 0, stream>>>(xn, WoutT, bout, out);
}

// Round 12
// 1375.043 us; speedup vs baseline: 1.3598x; 1.1005x over previous
//
#include <hip/hip_runtime.h>
#include <math.h>

#define BB 2
#define SS 2048
#define EE 512
#define HH 8
#define HD 64
#define LL 4
#define VV 50257
#define NTOK (BB*SS)
#define VPAD2 50432   // 197 * 256

typedef __bf16 bf16_t;
typedef bf16_t bf16x8 __attribute__((ext_vector_type(8)));
typedef float  f32x4  __attribute__((ext_vector_type(4)));

__device__ __forceinline__ void gload_lds16(const void* g, void* l) {
  __builtin_amdgcn_global_load_lds(
      (const __attribute__((address_space(1))) void*)g,
      (__attribute__((address_space(3))) void*)l, 16, 0, 0);
}

// ---------------- embedding + sinusoidal PE ----------------
__global__ __launch_bounds__(256) void embed_kernel(const int* __restrict__ ids,
                                                    const float* __restrict__ emb,
                                                    float* __restrict__ x) {
  int idx = blockIdx.x * 256 + threadIdx.x;
  int e   = idx & (EE - 1);
  int tok = idx >> 9;
  int s   = tok & (SS - 1);
  int id  = ids[tok];
  float freq = expf((float)(e & ~1) * -0.01798894604f);
  float ang  = (float)s * freq;
  float pe   = (e & 1) ? cosf(ang) : sinf(ang);
  x[idx] = emb[(size_t)id * EE + e] + pe;
}

// ---------------- LayerNorm: fp32 in -> bf16 out, one wave per row ----------------
__global__ __launch_bounds__(256) void ln_kernel(const float* __restrict__ in,
                                                 bf16_t* __restrict__ out,
                                                 const float* __restrict__ g,
                                                 const float* __restrict__ b) {
  int wv = threadIdx.x >> 6, lane = threadIdx.x & 63;
  int row = blockIdx.x * 4 + wv;
  const float4* r = reinterpret_cast<const float4*>(in + (size_t)row * EE) + lane * 2;
  float4 v0 = r[0], v1 = r[1];
  float s = v0.x + v0.y + v0.z + v0.w + v1.x + v1.y + v1.z + v1.w;
#pragma unroll
  for (int o = 32; o > 0; o >>= 1) s += __shfl_xor(s, o);
  float mean = s * (1.f / EE);
  float d0 = v0.x-mean, d1 = v0.y-mean, d2 = v0.z-mean, d3 = v0.w-mean;
  float d4 = v1.x-mean, d5 = v1.y-mean, d6 = v1.z-mean, d7 = v1.w-mean;
  float var = d0*d0+d1*d1+d2*d2+d3*d3+d4*d4+d5*d5+d6*d6+d7*d7;
#pragma unroll
  for (int o = 32; o > 0; o >>= 1) var += __shfl_xor(var, o);
  float inv = rsqrtf(var * (1.f / EE) + 1e-5f);
  const float4* gp = reinterpret_cast<const float4*>(g) + lane * 2;
  const float4* bp = reinterpret_cast<const float4*>(b) + lane * 2;
  float4 g0 = gp[0], g1 = gp[1], b0 = bp[0], b1 = bp[1];
  bf16_t tmp[8];
  tmp[0] = (bf16_t)(d0*inv*g0.x + b0.x); tmp[1] = (bf16_t)(d1*inv*g0.y + b0.y);
  tmp[2] = (bf16_t)(d2*inv*g0.z + b0.z); tmp[3] = (bf16_t)(d3*inv*g0.w + b0.w);
  tmp[4] = (bf16_t)(d4*inv*g1.x + b1.x); tmp[5] = (bf16_t)(d5*inv*g1.y + b1.y);
  tmp[6] = (bf16_t)(d6*inv*g1.z + b1.z); tmp[7] = (bf16_t)(d7*inv*g1.w + b1.w);
  *reinterpret_cast<bf16x8*>(out + (size_t)row * EE + lane * 8) = *reinterpret_cast<bf16x8*>(tmp);
}

// ---------------- weight transpose+convert: fp32 [K][N] -> bf16 [N][K] ----------------
__device__ __forceinline__ void transpose_tile(const float* __restrict__ ip,
                                               bf16_t* __restrict__ op,
                                               int k0, int n0, int ldin, int ldout,
                                               int Nvalid, float* T) {
  int t = threadIdx.x;
  int r = t >> 2, cb = (t & 3) * 16;
#pragma unroll
  for (int i = 0; i < 16; i++) {
    int n = n0 + cb + i;
    T[r * 65 + cb + i] = (n < Nvalid) ? ip[(size_t)(k0 + r) * ldin + n] : 0.f;
  }
  __syncthreads();
  bf16_t tmp[16];
#pragma unroll
  for (int i = 0; i < 16; i++) tmp[i] = (bf16_t)T[(cb + i) * 65 + r];
  bf16_t* o = op + (size_t)(n0 + r) * ldout + k0 + cb;
  *reinterpret_cast<bf16x8*>(o)     = *reinterpret_cast<bf16x8*>(&tmp[0]);
  *reinterpret_cast<bf16x8*>(o + 8) = *reinterpret_cast<bf16x8*>(&tmp[8]);
}

__global__ __launch_bounds__(256) void wconv_kernel(const float* __restrict__ in,
                                                    bf16_t* __restrict__ out,
                                                    int ldin, int ldout, int Nvalid,
                                                    long zin, long zout) {
  __shared__ float T[64 * 65];
  transpose_tile(in + (size_t)blockIdx.z * zin, out + (size_t)blockIdx.z * zout,
                 blockIdx.x * 64, blockIdx.y * 64, ldin, ldout, Nvalid, T);
}

__global__ __launch_bounds__(256) void wconv_qkv_kernel(const float* __restrict__ Wq,
                                                        const float* __restrict__ Wk,
                                                        const float* __restrict__ Wv,
                                                        bf16_t* __restrict__ out) {
  __shared__ float T[64 * 65];
  int z = blockIdx.z;
  int l = z / 24, rem = z % 24, sec = rem >> 3, h = rem & 7;
  const float* W = sec == 0 ? Wq : (sec == 1 ? Wk : Wv);
  const float* ip = W + (size_t)(l * 8 + h) * (EE * HD);
  bf16_t* op = out + (size_t)l * (1536 * 512) + (size_t)(sec * 512 + h * 64) * 512;
  transpose_tile(ip, op, blockIdx.x * 64, 0, HD, EE, HD, T);
}

// ---------------- 64/128-tile bf16 MFMA GEMM (layer GEMMs), single-buffer ----
// Fragment-major LDS (0 conflicts).
// MODE: 0=QKV scatter, 1=bias+GELU->bf16, 2=(+bias)+residual f32.
template<int MODE, int TM>
__global__ __launch_bounds__(256) void gemm_bf16(
    const bf16_t* __restrict__ A, const bf16_t* __restrict__ Bt,
    int M, int N, int K,
    const float* __restrict__ bias,
    float* __restrict__ Cf, bf16_t* __restrict__ Cb,
    bf16_t* __restrict__ qo, bf16_t* __restrict__ ko, bf16_t* __restrict__ vo) {
  constexpr int MI = TM / 32;
  __shared__ __align__(16) bf16_t As[TM * 64];
  __shared__ __align__(16) bf16_t Bs[128 * 64];
  int tid = threadIdx.x, lane = tid & 63, w = tid >> 6;
  int lr = lane & 15, lg = lane >> 4;
  int m0 = blockIdx.y * TM, n0 = blockIdx.x * 128;
  f32x4 acc[MI][4];
#pragma unroll
  for (int i = 0; i < MI; i++)
#pragma unroll
    for (int j = 0; j < 4; j++) acc[i][j] = (f32x4){0.f, 0.f, 0.f, 0.f};
  int wr = w >> 1, wc = w & 1;

  const bf16_t* Abase = A  + (size_t)(m0 + lr) * K + lg * 8;
  const bf16_t* Bbase = Bt + (size_t)(n0 + lr) * K + lg * 8;

  for (int k0 = 0; k0 < K; k0 += 64) {
#pragma unroll
    for (int i = 0; i < MI; i++) {
      int c = w * MI + i;
      gload_lds16(Abase + (size_t)(c >> 1) * 16 * K + k0 + (c & 1) * 32,
                  (char*)As + c * 1024);
    }
#pragma unroll
    for (int i = 0; i < 4; i++) {
      int c = w * 4 + i;
      gload_lds16(Bbase + (size_t)(c >> 1) * 16 * K + k0 + (c & 1) * 32,
                  (char*)Bs + c * 1024);
    }
    __syncthreads();
#pragma unroll
    for (int kk = 0; kk < 2; kk++) {
      bf16x8 afr[MI], bfr[4];
#pragma unroll
      for (int mi = 0; mi < MI; mi++)
        afr[mi] = *reinterpret_cast<const bf16x8*>(
            &As[(((wr * MI + mi) << 1) + kk) * 512 + lane * 8]);
#pragma unroll
      for (int ni = 0; ni < 4; ni++)
        bfr[ni] = *reinterpret_cast<const bf16x8*>(
            &Bs[(((wc * 4 + ni) << 1) + kk) * 512 + lane * 8]);
#pragma unroll
      for (int mi = 0; mi < MI; mi++)
#pragma unroll
        for (int ni = 0; ni < 4; ni++)
          acc[mi][ni] = __builtin_amdgcn_mfma_f32_16x16x32_bf16(afr[mi], bfr[ni], acc[mi][ni], 0, 0, 0);
    }
    __syncthreads();
  }

#pragma unroll
  for (int mi = 0; mi < MI; mi++)
#pragma unroll
    for (int ni = 0; ni < 4; ni++) {
      int colg = n0 + wc * 64 + ni * 16 + lr;
#pragma unroll
      for (int j = 0; j < 4; j++) {
        int rowg = m0 + wr * (TM / 2) + mi * 16 + lg * 4 + j;
        float v = acc[mi][ni][j];
        if (MODE == 0) {
          int sec = colg >> 9, cc = colg & 511, hh = cc >> 6, dd = cc & 63;
          int bi = rowg >> 11, s = rowg & 2047;
          if (sec == 0)      qo[(((size_t)bi * HH + hh) * SS + s) * HD + dd] = (bf16_t)(v * 0.125f);
          else if (sec == 1) ko[(((size_t)bi * HH + hh) * SS + s) * HD + dd] = (bf16_t)v;
          else               vo[(((size_t)bi * HH + hh) * HD + dd) * SS + s] = (bf16_t)v;
        } else if (MODE == 1) {
          v += bias[colg];
          v = 0.5f * v * (1.f + erff(v * 0.70710678f));
          Cb[(size_t)rowg * N + colg] = (bf16_t)v;
        } else {
          if (bias) v += bias[colg];
          Cf[(size_t)rowg * EE + colg] += v;
        }
      }
    }
}

// ---------------- vocab GEMM: 256², SINGLE-buffer (64KB -> 2 blocks/CU), -----
// N-fastest grid (write locality, r8-proven). TLP-overlap experiment: two
// co-resident blocks hide each other's stage-drain stalls (m114 regime).
__global__ __launch_bounds__(512) void gemm256_out(
    const bf16_t* __restrict__ A, const bf16_t* __restrict__ Bt,
    const float* __restrict__ bias, float* __restrict__ C) {
  __shared__ __align__(16) bf16_t As[256 * 64];   // 32 KB
  __shared__ __align__(16) bf16_t Bs[256 * 64];   // 32 KB
  int tid = threadIdx.x, lane = tid & 63, w = tid >> 6;
  int lr = lane & 15, lg = lane >> 4;
  int bid = blockIdx.x;
  int n0 = (bid % 197) * 256, m0 = (bid / 197) * 256;   // N-fastest
  int wr = w >> 2, wc = w & 3;
  f32x4 acc[8][4];
#pragma unroll
  for (int i = 0; i < 8; i++)
#pragma unroll
    for (int j = 0; j < 4; j++) acc[i][j] = (f32x4){0.f, 0.f, 0.f, 0.f};

  const bf16_t* Abase = A  + (size_t)(m0 + lr) * 512 + lg * 8;
  const bf16_t* Bbase = Bt + (size_t)(n0 + lr) * 512 + lg * 8;

  for (int k0 = 0; k0 < 512; k0 += 64) {
#pragma unroll
    for (int i = 0; i < 4; i++) {
      int c = w * 4 + i;
      gload_lds16(Abase + (size_t)(c >> 1) * 16 * 512 + k0 + (c & 1) * 32,
                  (char*)As + c * 1024);
      gload_lds16(Bbase + (size_t)(c >> 1) * 16 * 512 + k0 + (c & 1) * 32,
                  (char*)Bs + c * 1024);
    }
    __syncthreads();
#pragma unroll
    for (int kk = 0; kk < 2; kk++) {
      bf16x8 afr[8], bfr[4];
#pragma unroll
      for (int mi = 0; mi < 8; mi++)
        afr[mi] = *reinterpret_cast<const bf16x8*>(
            &As[(((wr * 8 + mi) << 1) + kk) * 512 + lane * 8]);
#pragma unroll
      for (int ni = 0; ni < 4; ni++)
        bfr[ni] = *reinterpret_cast<const bf16x8*>(
            &Bs[(((wc * 4 + ni) << 1) + kk) * 512 + lane * 8]);
#pragma unroll
      for (int mi = 0; mi < 8; mi++)
#pragma unroll
        for (int ni = 0; ni < 4; ni++)
          acc[mi][ni] = __builtin_amdgcn_mfma_f32_16x16x32_bf16(afr[mi], bfr[ni], acc[mi][ni], 0, 0, 0);
    }
    __syncthreads();
  }

#pragma unroll
  for (int mi = 0; mi < 8; mi++)
#pragma unroll
    for (int ni = 0; ni < 4; ni++) {
      int colg = n0 + wc * 64 + ni * 16 + lr;
      if (colg < VV) {
        float bs = bias[colg];
#pragma unroll
        for (int j = 0; j < 4; j++) {
          int rowg = m0 + wr * 128 + mi * 16 + lg * 4 + j;
          C[(size_t)rowg * VV + colg] = acc[mi][ni][j] + bs;
        }
      }
    }
}

// ---------------- flash attention v3: QBLK=64, load-balanced, 2 blocks/CU ----
// Causal work per q-block varies 1..32 tiles. With 512 blocks and the remap
// qq = qi<16 ? qi : 47-qi, co-resident block pairs (bid, bid+256) sum to a
// CONSTANT 33 tiles -> no straggler CU. LDS 58KB -> 2 blocks/CU (stall overlap).
// K/V staged fragment-major via global_load_lds dbuf, issue-early prefetch.
#define QBLK 64
#define KVB 64
__global__ __launch_bounds__(256) void attn_kernel(
    const bf16_t* __restrict__ qb,   // [B,H,S,D], pre-scaled by 1/8
    const bf16_t* __restrict__ kb,   // [B,H,S,D]
    const bf16_t* __restrict__ vT,   // [B,H,D,S]
    const int* __restrict__ amask,   // [B,S]
    bf16_t* __restrict__ ab) {       // [B*S][E]
  __shared__ bf16_t Qs[QBLK][72];                    // 9 KB
  __shared__ bf16_t Ps[QBLK][72];                    // 9 KB
  __shared__ __align__(16) bf16_t Ks[2][KVB * 64];   // 16 KB
  __shared__ __align__(16) bf16_t Vs[2][KVB * 64];   // 16 KB
  __shared__ float kmAll[SS];                        // 8 KB  (58 KB total)
  int tid = threadIdx.x, lane = tid & 63, w = tid >> 6;
  int lr = lane & 15, lg = lane >> 4;
  int bid = blockIdx.x;
  int bh = bid & 15;
  int qi = bid >> 4;                         // 0..31
  int qq = (qi < 16) ? qi : 47 - qi;         // balance pairing (bid, bid+256)
  int q0 = qq * QBLK;
  int b = bh >> 3, h = bh & 7;
  const bf16_t* Qg = qb + (size_t)bh * SS * HD;
  const bf16_t* Kg = kb + (size_t)bh * SS * HD;
  const bf16_t* Vg = vT + (size_t)bh * HD * SS;

  { // stage Q tile: 64 rows x 128B, 4 threads/row
    int r = tid >> 2, c = (tid & 3) * 16;
    const uint4* s = reinterpret_cast<const uint4*>(Qg + (size_t)(q0 + r) * HD + c);
    uint4 a0 = s[0], a1 = s[1];
    *reinterpret_cast<uint4*>(&Qs[r][c])     = a0;
    *reinterpret_cast<uint4*>(&Qs[r][c + 8]) = a1;
  }
#pragma unroll
  for (int i = 0; i < 8; i++) {
    int s = i * 256 + tid;
    kmAll[s] = amask[b * SS + s] ? 0.f : -1e30f;
  }

  auto stageKV = [&](int buf, int kv0) {   // 16 sub-blocks (8 K + 8 V), 4/wave
#pragma unroll
    for (int i = 0; i < 4; i++) {
      int c = w * 4 + i;
      if (c < 8) {
        gload_lds16(Kg + (size_t)(kv0 + (c >> 1) * 16 + lr) * HD + (c & 1) * 32 + lg * 8,
                    (char*)&Ks[buf][0] + c * 1024);
      } else {
        int cc = c - 8;
        gload_lds16(Vg + (size_t)((cc >> 1) * 16 + lr) * SS + kv0 + (cc & 1) * 32 + lg * 8,
                    (char*)&Vs[buf][0] + cc * 1024);
      }
    }
  };

  f32x4 o[4];
  f32x4 m_run, l_run;
  m_run = (f32x4){-1e30f, -1e30f, -1e30f, -1e30f};
  l_run = (f32x4){0.f, 0.f, 0.f, 0.f};
#pragma unroll
  for (int nd = 0; nd < 4; nd++) o[nd] = (f32x4){0.f, 0.f, 0.f, 0.f};

  stageKV(0, 0);
  __syncthreads();   // drains vm+lgkm: Q, kmAll, tile-0 K/V all visible

  int ntile = qq + 1;
  for (int t = 0; t < ntile; t++) {
    int buf = t & 1;
    int kv0 = t * KVB;
    if (t + 1 < ntile) stageKV(buf ^ 1, kv0 + KVB);  // issue-early prefetch

    // QK^T
    f32x4 sc[4];
#pragma unroll
    for (int ni = 0; ni < 4; ni++) sc[ni] = (f32x4){0.f, 0.f, 0.f, 0.f};
#pragma unroll
    for (int kk = 0; kk < 2; kk++) {
      bf16x8 af = *reinterpret_cast<const bf16x8*>(&Qs[w * 16 + lr][kk * 32 + lg * 8]);
      bf16x8 bf[4];
#pragma unroll
      for (int ni = 0; ni < 4; ni++)
        bf[ni] = *reinterpret_cast<const bf16x8*>(&Ks[buf][((ni << 1) + kk) * 512 + lane * 8]);
#pragma unroll
      for (int ni = 0; ni < 4; ni++)
        sc[ni] = __builtin_amdgcn_mfma_f32_16x16x32_bf16(af, bf[ni], sc[ni], 0, 0, 0);
    }

    // online softmax (one 16-row frag per wave)
    {
      int qrb = q0 + w * 16 + lg * 4;
      float kmv[4];
#pragma unroll
      for (int ni = 0; ni < 4; ni++) kmv[ni] = kmAll[kv0 + ni * 16 + lr];
#pragma unroll
      for (int ni = 0; ni < 4; ni++) {
        int kg = kv0 + ni * 16 + lr;
#pragma unroll
        for (int j = 0; j < 4; j++) {
          float s = sc[ni][j] + kmv[ni];
          sc[ni][j] = (kg <= qrb + j) ? s : -1e30f;
        }
      }
      f32x4 rmax = sc[0];
#pragma unroll
      for (int ni = 1; ni < 4; ni++)
#pragma unroll
        for (int j = 0; j < 4; j++) rmax[j] = fmaxf(rmax[j], sc[ni][j]);
#pragma unroll
      for (int msk = 1; msk <= 8; msk <<= 1)
#pragma unroll
        for (int j = 0; j < 4; j++) rmax[j] = fmaxf(rmax[j], __shfl_xor(rmax[j], msk));
      f32x4 mnew, corr;
#pragma unroll
      for (int j = 0; j < 4; j++) {
        mnew[j] = fmaxf(m_run[j], rmax[j]);
        corr[j] = __expf(m_run[j] - mnew[j]);
      }
      m_run = mnew;
      f32x4 rs = (f32x4){0.f, 0.f, 0.f, 0.f};
#pragma unroll
      for (int ni = 0; ni < 4; ni++) {
#pragma unroll
        for (int j = 0; j < 4; j++) {
          float p = __expf(sc[ni][j] - mnew[j]);
          rs[j] += p;
          Ps[w * 16 + lg * 4 + j][ni * 16 + lr] = (bf16_t)p;
        }
      }
#pragma unroll
      for (int msk = 1; msk <= 8; msk <<= 1)
#pragma unroll
        for (int j = 0; j < 4; j++) rs[j] += __shfl_xor(rs[j], msk);
#pragma unroll
      for (int j = 0; j < 4; j++) l_run[j] = l_run[j] * corr[j] + rs[j];
#pragma unroll
      for (int nd = 0; nd < 4; nd++) o[nd] = o[nd] * corr;
    }

    // PV (Ps rows are wave-private)
#pragma unroll
    for (int kc = 0; kc < 2; kc++) {
      bf16x8 pa = *reinterpret_cast<const bf16x8*>(&Ps[w * 16 + lr][kc * 32 + lg * 8]);
      bf16x8 vb[4];
#pragma unroll
      for (int nd = 0; nd < 4; nd++)
        vb[nd] = *reinterpret_cast<const bf16x8*>(&Vs[buf][((nd << 1) + kc) * 512 + lane * 8]);
#pragma unroll
      for (int nd = 0; nd < 4; nd++)
        o[nd] = __builtin_amdgcn_mfma_f32_16x16x32_bf16(pa, vb[nd], o[nd], 0, 0, 0);
    }
    asm volatile("s_waitcnt vmcnt(0)" ::: "memory");
    asm volatile("s_barrier" ::: "memory");
  }

  f32x4 linv;
#pragma unroll
  for (int j = 0; j < 4; j++) linv[j] = 1.f / l_run[j];
#pragma unroll
  for (int nd = 0; nd < 4; nd++)
#pragma unroll
    for (int j = 0; j < 4; j++) {
      int rowg = b * SS + q0 + w * 16 + lg * 4 + j;
      int col = h * HD + nd * 16 + lr;
      ab[(size_t)rowg * EE + col] = (bf16_t)(o[nd][j] * linv[j]);
    }
}

extern "C" void kernel_launch(void* const* d_in, const int* in_sizes, int n_in,
                              void* d_out, int out_size, void* d_ws, size_t ws_size,
                              hipStream_t stream) {
  const int*   ids   = (const int*)d_in[0];
  const int*   amask = (const int*)d_in[1];
  const float* emb   = (const float*)d_in[2];
  const float* Wq    = (const float*)d_in[3];
  const float* Wk    = (const float*)d_in[4];
  const float* Wv    = (const float*)d_in[5];
  const float* Wo    = (const float*)d_in[6];
  const float* ln1g  = (const float*)d_in[7];
  const float* ln1b  = (const float*)d_in[8];
  const float* ln2g  = (const float*)d_in[9];
  const float* ln2b  = (const float*)d_in[10];
  const float* fw1   = (const float*)d_in[11];
  const float* fb1   = (const float*)d_in[12];
  const float* fw2   = (const float*)d_in[13];
  const float* fb2   = (const float*)d_in[14];
  const float* lnfg  = (const float*)d_in[15];
  const float* lnfb  = (const float*)d_in[16];
  const float* Wout  = (const float*)d_in[17];
  const float* bout  = (const float*)d_in[18];
  float* out = (float*)d_out;

  // ws: x (8MB) | xn (4MB) | WoutT (51.7MB padded to 50432 rows)
  float*  x     = (float*)d_ws;
  bf16_t* xn    = (bf16_t*)((char*)d_ws + (8u << 20));
  bf16_t* WoutT = (bf16_t*)((char*)d_ws + (12u << 20));
  // d_out head as scratch (57MB of 824MB; fully overwritten by final GEMM)
  char* sc = (char*)d_out;
  bf16_t* qbuf = (bf16_t*)(sc);
  bf16_t* kbuf = (bf16_t*)(sc + 4194304);
  bf16_t* vTb  = (bf16_t*)(sc + 8388608);
  bf16_t* ab   = (bf16_t*)(sc + 12582912);
  bf16_t* hb   = (bf16_t*)(sc + 16777216);
  bf16_t* Wqkv = (bf16_t*)(sc + 33554432);
  bf16_t* WoT  = (bf16_t*)(sc + 39845888);
  bf16_t* W1T  = (bf16_t*)(sc + 41943040);
  bf16_t* W2T  = (bf16_t*)(sc + 50331648);

  wconv_qkv_kernel<<<dim3(8, 1, 96), 256, 0, stream>>>(Wq, Wk, Wv, Wqkv);
  wconv_kernel<<<dim3(8, 8, LL), 256, 0, stream>>>(Wo, WoT, 512, 512, 512,
                                                   512L * 512, 512L * 512);
  wconv_kernel<<<dim3(8, 32, LL), 256, 0, stream>>>(fw1, W1T, 2048, 512, 2048,
                                                    512L * 2048, 2048L * 512);
  wconv_kernel<<<dim3(32, 8, LL), 256, 0, stream>>>(fw2, W2T, 512, 2048, 512,
                                                    2048L * 512, 512L * 2048);
  wconv_kernel<<<dim3(8, VPAD2 / 64, 1), 256, 0, stream>>>(Wout, WoutT, VV, 512, VV, 0, 0);

  embed_kernel<<<NTOK * EE / 256, 256, 0, stream>>>(ids, emb, x);

  for (int l = 0; l < LL; l++) {
    ln_kernel<<<NTOK / 4, 256, 0, stream>>>(x, xn, ln1g + l * EE, ln1b + l * EE);
    gemm_bf16<0, 128><<<dim3(12, 32), 256, 0, stream>>>(xn, Wqkv + (size_t)l * 1536 * 512,
        NTOK, 1536, 512, nullptr, nullptr, nullptr, qbuf, kbuf, vTb);
    attn_kernel<<<dim3(512), 256, 0, stream>>>(qbuf, kbuf, vTb, amask, ab);
    gemm_bf16<2, 64><<<dim3(4, 64), 256, 0, stream>>>(ab, WoT + (size_t)l * 512 * 512,
        NTOK, 512, 512, nullptr, x, nullptr, nullptr, nullptr, nullptr);
    ln_kernel<<<NTOK / 4, 256, 0, stream>>>(x, xn, ln2g + l * EE, ln2b + l * EE);
    gemm_bf16<1, 128><<<dim3(16, 32), 256, 0, stream>>>(xn, W1T + (size_t)l * 2048 * 512,
        NTOK, 2048, 512, fb1 + l * 2048, nullptr, hb, nullptr, nullptr, nullptr);
    gemm_bf16<2, 64><<<dim3(4, 64), 256, 0, stream>>>(hb, W2T + (size_t)l * 512 * 2048,
        NTOK, 512, 2048, fb2 + l * EE, x, nullptr, nullptr, nullptr, nullptr);
  }
  ln_kernel<<<NTOK / 4, 256, 0, stream>>>(x, xn, lnfg, lnfb);
  gemm256_out<<<dim3(16 * (VPAD2 / 256)), 512, 0, stream>>>(xn, WoutT, bout, out);
}

// Round 13
// 1362.628 us; speedup vs baseline: 1.3722x; 1.0091x over previous
//
#include <hip/hip_runtime.h>
#include <math.h>

#define BB 2
#define SS 2048
#define EE 512
#define HH 8
#define HD 64
#define LL 4
#define VV 50257
#define NTOK (BB*SS)
#define VPAD2 50432   // 197 * 256

typedef __bf16 bf16_t;
typedef bf16_t bf16x8 __attribute__((ext_vector_type(8)));
typedef float  f32x4  __attribute__((ext_vector_type(4)));

__device__ __forceinline__ void gload_lds16(const void* g, void* l) {
  __builtin_amdgcn_global_load_lds(
      (const __attribute__((address_space(1))) void*)g,
      (__attribute__((address_space(3))) void*)l, 16, 0, 0);
}

// ---------------- embedding + sinusoidal PE ----------------
__global__ __launch_bounds__(256) void embed_kernel(const int* __restrict__ ids,
                                                    const float* __restrict__ emb,
                                                    float* __restrict__ x) {
  int idx = blockIdx.x * 256 + threadIdx.x;
  int e   = idx & (EE - 1);
  int tok = idx >> 9;
  int s   = tok & (SS - 1);
  int id  = ids[tok];
  float freq = expf((float)(e & ~1) * -0.01798894604f);
  float ang  = (float)s * freq;
  float pe   = (e & 1) ? cosf(ang) : sinf(ang);
  x[idx] = emb[(size_t)id * EE + e] + pe;
}

// ---------------- LayerNorm: fp32 in -> bf16 out, one wave per row ----------------
__global__ __launch_bounds__(256) void ln_kernel(const float* __restrict__ in,
                                                 bf16_t* __restrict__ out,
                                                 const float* __restrict__ g,
                                                 const float* __restrict__ b) {
  int wv = threadIdx.x >> 6, lane = threadIdx.x & 63;
  int row = blockIdx.x * 4 + wv;
  const float4* r = reinterpret_cast<const float4*>(in + (size_t)row * EE) + lane * 2;
  float4 v0 = r[0], v1 = r[1];
  float s = v0.x + v0.y + v0.z + v0.w + v1.x + v1.y + v1.z + v1.w;
#pragma unroll
  for (int o = 32; o > 0; o >>= 1) s += __shfl_xor(s, o);
  float mean = s * (1.f / EE);
  float d0 = v0.x-mean, d1 = v0.y-mean, d2 = v0.z-mean, d3 = v0.w-mean;
  float d4 = v1.x-mean, d5 = v1.y-mean, d6 = v1.z-mean, d7 = v1.w-mean;
  float var = d0*d0+d1*d1+d2*d2+d3*d3+d4*d4+d5*d5+d6*d6+d7*d7;
#pragma unroll
  for (int o = 32; o > 0; o >>= 1) var += __shfl_xor(var, o);
  float inv = rsqrtf(var * (1.f / EE) + 1e-5f);
  const float4* gp = reinterpret_cast<const float4*>(g) + lane * 2;
  const float4* bp = reinterpret_cast<const float4*>(b) + lane * 2;
  float4 g0 = gp[0], g1 = gp[1], b0 = bp[0], b1 = bp[1];
  bf16_t tmp[8];
  tmp[0] = (bf16_t)(d0*inv*g0.x + b0.x); tmp[1] = (bf16_t)(d1*inv*g0.y + b0.y);
  tmp[2] = (bf16_t)(d2*inv*g0.z + b0.z); tmp[3] = (bf16_t)(d3*inv*g0.w + b0.w);
  tmp[4] = (bf16_t)(d4*inv*g1.x + b1.x); tmp[5] = (bf16_t)(d5*inv*g1.y + b1.y);
  tmp[6] = (bf16_t)(d6*inv*g1.z + b1.z); tmp[7] = (bf16_t)(d7*inv*g1.w + b1.w);
  *reinterpret_cast<bf16x8*>(out + (size_t)row * EE + lane * 8) = *reinterpret_cast<bf16x8*>(tmp);
}

// ---------------- weight transpose+convert: fp32 [K][N] -> bf16 [N][K] ----------------
__device__ __forceinline__ void transpose_tile(const float* __restrict__ ip,
                                               bf16_t* __restrict__ op,
                                               int k0, int n0, int ldin, int ldout,
                                               int Nvalid, float* T) {
  int t = threadIdx.x;
  int r = t >> 2, cb = (t & 3) * 16;
#pragma unroll
  for (int i = 0; i < 16; i++) {
    int n = n0 + cb + i;
    T[r * 65 + cb + i] = (n < Nvalid) ? ip[(size_t)(k0 + r) * ldin + n] : 0.f;
  }
  __syncthreads();
  bf16_t tmp[16];
#pragma unroll
  for (int i = 0; i < 16; i++) tmp[i] = (bf16_t)T[(cb + i) * 65 + r];
  bf16_t* o = op + (size_t)(n0 + r) * ldout + k0 + cb;
  *reinterpret_cast<bf16x8*>(o)     = *reinterpret_cast<bf16x8*>(&tmp[0]);
  *reinterpret_cast<bf16x8*>(o + 8) = *reinterpret_cast<bf16x8*>(&tmp[8]);
}

__global__ __launch_bounds__(256) void wconv_kernel(const float* __restrict__ in,
                                                    bf16_t* __restrict__ out,
                                                    int ldin, int ldout, int Nvalid,
                                                    long zin, long zout) {
  __shared__ float T[64 * 65];
  transpose_tile(in + (size_t)blockIdx.z * zin, out + (size_t)blockIdx.z * zout,
                 blockIdx.x * 64, blockIdx.y * 64, ldin, ldout, Nvalid, T);
}

__global__ __launch_bounds__(256) void wconv_qkv_kernel(const float* __restrict__ Wq,
                                                        const float* __restrict__ Wk,
                                                        const float* __restrict__ Wv,
                                                        bf16_t* __restrict__ out) {
  __shared__ float T[64 * 65];
  int z = blockIdx.z;
  int l = z / 24, rem = z % 24, sec = rem >> 3, h = rem & 7;
  const float* W = sec == 0 ? Wq : (sec == 1 ? Wk : Wv);
  const float* ip = W + (size_t)(l * 8 + h) * (EE * HD);
  bf16_t* op = out + (size_t)l * (1536 * 512) + (size_t)(sec * 512 + h * 64) * 512;
  transpose_tile(ip, op, blockIdx.x * 64, 0, HD, EE, HD, T);
}

// ---------------- layer GEMMs: 2-phase counted-vmcnt dbuf (T3/T4 minimum) ----
// Fragment-major LDS (0 conflicts). Per K-step: {stage(next); vmcnt(L);
// s_barrier; ds_read+MFMA; s_barrier} -- next-tile loads stay in flight across
// the barriers (raw s_barrier, NOT __syncthreads, so no vmcnt(0) drain).
// MODE: 0=QKV scatter, 1=bias+GELU->bf16, 2=(+bias)+residual f32.
template<int MODE, int TM>
__global__ __launch_bounds__(256) void gemm_bf16(
    const bf16_t* __restrict__ A, const bf16_t* __restrict__ Bt,
    int M, int N, int K,
    const float* __restrict__ bias,
    float* __restrict__ Cf, bf16_t* __restrict__ Cb,
    bf16_t* __restrict__ qo, bf16_t* __restrict__ ko, bf16_t* __restrict__ vo) {
  constexpr int MI = TM / 32;
  constexpr int LW = MI + 4;                 // loads per wave per stage
  __shared__ __align__(16) bf16_t As[2][TM * 64];
  __shared__ __align__(16) bf16_t Bs[2][128 * 64];
  int tid = threadIdx.x, lane = tid & 63, w = tid >> 6;
  int lr = lane & 15, lg = lane >> 4;
  int m0 = blockIdx.y * TM, n0 = blockIdx.x * 128;
  f32x4 acc[MI][4];
#pragma unroll
  for (int i = 0; i < MI; i++)
#pragma unroll
    for (int j = 0; j < 4; j++) acc[i][j] = (f32x4){0.f, 0.f, 0.f, 0.f};
  int wr = w >> 1, wc = w & 1;

  const bf16_t* Abase = A  + (size_t)(m0 + lr) * K + lg * 8;
  const bf16_t* Bbase = Bt + (size_t)(n0 + lr) * K + lg * 8;

  auto stage = [&](int buf, int k0) {
#pragma unroll
    for (int i = 0; i < MI; i++) {
      int c = w * MI + i;
      gload_lds16(Abase + (size_t)(c >> 1) * 16 * K + k0 + (c & 1) * 32,
                  (char*)&As[buf][0] + c * 1024);
    }
#pragma unroll
    for (int i = 0; i < 4; i++) {
      int c = w * 4 + i;
      gload_lds16(Bbase + (size_t)(c >> 1) * 16 * K + k0 + (c & 1) * 32,
                  (char*)&Bs[buf][0] + c * 1024);
    }
  };

  int nk = K >> 6;
  stage(0, 0);
  for (int k = 0; k < nk; k++) {
    int cur = k & 1;
    if (k + 1 < nk) {
      stage(cur ^ 1, (k + 1) << 6);
      asm volatile("s_waitcnt vmcnt(%0)" :: "i"(LW) : "memory");  // cur landed
    } else {
      asm volatile("s_waitcnt vmcnt(0)" ::: "memory");
    }
    __builtin_amdgcn_s_barrier();
#pragma unroll
    for (int kk = 0; kk < 2; kk++) {
      bf16x8 afr[MI], bfr[4];
#pragma unroll
      for (int mi = 0; mi < MI; mi++)
        afr[mi] = *reinterpret_cast<const bf16x8*>(
            &As[cur][(((wr * MI + mi) << 1) + kk) * 512 + lane * 8]);
#pragma unroll
      for (int ni = 0; ni < 4; ni++)
        bfr[ni] = *reinterpret_cast<const bf16x8*>(
            &Bs[cur][(((wc * 4 + ni) << 1) + kk) * 512 + lane * 8]);
#pragma unroll
      for (int mi = 0; mi < MI; mi++)
#pragma unroll
        for (int ni = 0; ni < 4; ni++)
          acc[mi][ni] = __builtin_amdgcn_mfma_f32_16x16x32_bf16(afr[mi], bfr[ni], acc[mi][ni], 0, 0, 0);
    }
    __builtin_amdgcn_s_barrier();   // all waves done reading cur before reuse
  }

#pragma unroll
  for (int mi = 0; mi < MI; mi++)
#pragma unroll
    for (int ni = 0; ni < 4; ni++) {
      int colg = n0 + wc * 64 + ni * 16 + lr;
#pragma unroll
      for (int j = 0; j < 4; j++) {
        int rowg = m0 + wr * (TM / 2) + mi * 16 + lg * 4 + j;
        float v = acc[mi][ni][j];
        if (MODE == 0) {
          int sec = colg >> 9, cc = colg & 511, hh = cc >> 6, dd = cc & 63;
          int bi = rowg >> 11, s = rowg & 2047;
          if (sec == 0)      qo[(((size_t)bi * HH + hh) * SS + s) * HD + dd] = (bf16_t)(v * 0.125f);
          else if (sec == 1) ko[(((size_t)bi * HH + hh) * SS + s) * HD + dd] = (bf16_t)v;
          else               vo[(((size_t)bi * HH + hh) * HD + dd) * SS + s] = (bf16_t)v;
        } else if (MODE == 1) {
          v += bias[colg];
          v = 0.5f * v * (1.f + erff(v * 0.70710678f));
          Cb[(size_t)rowg * N + colg] = (bf16_t)v;
        } else {
          if (bias) v += bias[colg];
          Cf[(size_t)rowg * EE + colg] += v;
        }
      }
    }
}

// ---------------- vocab GEMM: 256², single-buffer, N-fastest (r12 best) ------
__global__ __launch_bounds__(512) void gemm256_out(
    const bf16_t* __restrict__ A, const bf16_t* __restrict__ Bt,
    const float* __restrict__ bias, float* __restrict__ C) {
  __shared__ __align__(16) bf16_t As[256 * 64];   // 32 KB
  __shared__ __align__(16) bf16_t Bs[256 * 64];   // 32 KB
  int tid = threadIdx.x, lane = tid & 63, w = tid >> 6;
  int lr = lane & 15, lg = lane >> 4;
  int bid = blockIdx.x;
  int n0 = (bid % 197) * 256, m0 = (bid / 197) * 256;   // N-fastest
  int wr = w >> 2, wc = w & 3;
  f32x4 acc[8][4];
#pragma unroll
  for (int i = 0; i < 8; i++)
#pragma unroll
    for (int j = 0; j < 4; j++) acc[i][j] = (f32x4){0.f, 0.f, 0.f, 0.f};

  const bf16_t* Abase = A  + (size_t)(m0 + lr) * 512 + lg * 8;
  const bf16_t* Bbase = Bt + (size_t)(n0 + lr) * 512 + lg * 8;

  for (int k0 = 0; k0 < 512; k0 += 64) {
#pragma unroll
    for (int i = 0; i < 4; i++) {
      int c = w * 4 + i;
      gload_lds16(Abase + (size_t)(c >> 1) * 16 * 512 + k0 + (c & 1) * 32,
                  (char*)As + c * 1024);
      gload_lds16(Bbase + (size_t)(c >> 1) * 16 * 512 + k0 + (c & 1) * 32,
                  (char*)Bs + c * 1024);
    }
    __syncthreads();
#pragma unroll
    for (int kk = 0; kk < 2; kk++) {
      bf16x8 afr[8], bfr[4];
#pragma unroll
      for (int mi = 0; mi < 8; mi++)
        afr[mi] = *reinterpret_cast<const bf16x8*>(
            &As[(((wr * 8 + mi) << 1) + kk) * 512 + lane * 8]);
#pragma unroll
      for (int ni = 0; ni < 4; ni++)
        bfr[ni] = *reinterpret_cast<const bf16x8*>(
            &Bs[(((wc * 4 + ni) << 1) + kk) * 512 + lane * 8]);
#pragma unroll
      for (int mi = 0; mi < 8; mi++)
#pragma unroll
        for (int ni = 0; ni < 4; ni++)
          acc[mi][ni] = __builtin_amdgcn_mfma_f32_16x16x32_bf16(afr[mi], bfr[ni], acc[mi][ni], 0, 0, 0);
    }
    __syncthreads();
  }

#pragma unroll
  for (int mi = 0; mi < 8; mi++)
#pragma unroll
    for (int ni = 0; ni < 4; ni++) {
      int colg = n0 + wc * 64 + ni * 16 + lr;
      if (colg < VV) {
        float bs = bias[colg];
#pragma unroll
        for (int j = 0; j < 4; j++) {
          int rowg = m0 + wr * 128 + mi * 16 + lg * 4 + j;
          C[(size_t)rowg * VV + colg] = acc[mi][ni][j] + bs;
        }
      }
    }
}

// ---------------- flash attention v3: QBLK=64, load-balanced, 2 blocks/CU ----
#define QBLK 64
#define KVB 64
__global__ __launch_bounds__(256) void attn_kernel(
    const bf16_t* __restrict__ qb,   // [B,H,S,D], pre-scaled by 1/8
    const bf16_t* __restrict__ kb,   // [B,H,S,D]
    const bf16_t* __restrict__ vT,   // [B,H,D,S]
    const int* __restrict__ amask,   // [B,S]
    bf16_t* __restrict__ ab) {       // [B*S][E]
  __shared__ bf16_t Qs[QBLK][72];
  __shared__ bf16_t Ps[QBLK][72];
  __shared__ __align__(16) bf16_t Ks[2][KVB * 64];
  __shared__ __align__(16) bf16_t Vs[2][KVB * 64];
  __shared__ float kmAll[SS];
  int tid = threadIdx.x, lane = tid & 63, w = tid >> 6;
  int lr = lane & 15, lg = lane >> 4;
  int bid = blockIdx.x;
  int bh = bid & 15;
  int qi = bid >> 4;
  int qq = (qi < 16) ? qi : 47 - qi;         // balance pairing (bid, bid+256)
  int q0 = qq * QBLK;
  int b = bh >> 3, h = bh & 7;
  const bf16_t* Qg = qb + (size_t)bh * SS * HD;
  const bf16_t* Kg = kb + (size_t)bh * SS * HD;
  const bf16_t* Vg = vT + (size_t)bh * HD * SS;

  { // stage Q tile
    int r = tid >> 2, c = (tid & 3) * 16;
    const uint4* s = reinterpret_cast<const uint4*>(Qg + (size_t)(q0 + r) * HD + c);
    uint4 a0 = s[0], a1 = s[1];
    *reinterpret_cast<uint4*>(&Qs[r][c])     = a0;
    *reinterpret_cast<uint4*>(&Qs[r][c + 8]) = a1;
  }
#pragma unroll
  for (int i = 0; i < 8; i++) {
    int s = i * 256 + tid;
    kmAll[s] = amask[b * SS + s] ? 0.f : -1e30f;
  }

  auto stageKV = [&](int buf, int kv0) {
#pragma unroll
    for (int i = 0; i < 4; i++) {
      int c = w * 4 + i;
      if (c < 8) {
        gload_lds16(Kg + (size_t)(kv0 + (c >> 1) * 16 + lr) * HD + (c & 1) * 32 + lg * 8,
                    (char*)&Ks[buf][0] + c * 1024);
      } else {
        int cc = c - 8;
        gload_lds16(Vg + (size_t)((cc >> 1) * 16 + lr) * SS + kv0 + (cc & 1) * 32 + lg * 8,
                    (char*)&Vs[buf][0] + cc * 1024);
      }
    }
  };

  f32x4 o[4];
  f32x4 m_run, l_run;
  m_run = (f32x4){-1e30f, -1e30f, -1e30f, -1e30f};
  l_run = (f32x4){0.f, 0.f, 0.f, 0.f};
#pragma unroll
  for (int nd = 0; nd < 4; nd++) o[nd] = (f32x4){0.f, 0.f, 0.f, 0.f};

  stageKV(0, 0);
  __syncthreads();

  int ntile = qq + 1;
  for (int t = 0; t < ntile; t++) {
    int buf = t & 1;
    int kv0 = t * KVB;
    if (t + 1 < ntile) stageKV(buf ^ 1, kv0 + KVB);

    // QK^T
    f32x4 sc[4];
#pragma unroll
    for (int ni = 0; ni < 4; ni++) sc[ni] = (f32x4){0.f, 0.f, 0.f, 0.f};
#pragma unroll
    for (int kk = 0; kk < 2; kk++) {
      bf16x8 af = *reinterpret_cast<const bf16x8*>(&Qs[w * 16 + lr][kk * 32 + lg * 8]);
      bf16x8 bf[4];
#pragma unroll
      for (int ni = 0; ni < 4; ni++)
        bf[ni] = *reinterpret_cast<const bf16x8*>(&Ks[buf][((ni << 1) + kk) * 512 + lane * 8]);
#pragma unroll
      for (int ni = 0; ni < 4; ni++)
        sc[ni] = __builtin_amdgcn_mfma_f32_16x16x32_bf16(af, bf[ni], sc[ni], 0, 0, 0);
    }

    // online softmax
    {
      int qrb = q0 + w * 16 + lg * 4;
      float kmv[4];
#pragma unroll
      for (int ni = 0; ni < 4; ni++) kmv[ni] = kmAll[kv0 + ni * 16 + lr];
#pragma unroll
      for (int ni = 0; ni < 4; ni++) {
        int kg = kv0 + ni * 16 + lr;
#pragma unroll
        for (int j = 0; j < 4; j++) {
          float s = sc[ni][j] + kmv[ni];
          sc[ni][j] = (kg <= qrb + j) ? s : -1e30f;
        }
      }
      f32x4 rmax = sc[0];
#pragma unroll
      for (int ni = 1; ni < 4; ni++)
#pragma unroll
        for (int j = 0; j < 4; j++) rmax[j] = fmaxf(rmax[j], sc[ni][j]);
#pragma unroll
      for (int msk = 1; msk <= 8; msk <<= 1)
#pragma unroll
        for (int j = 0; j < 4; j++) rmax[j] = fmaxf(rmax[j], __shfl_xor(rmax[j], msk));
      f32x4 mnew, corr;
#pragma unroll
      for (int j = 0; j < 4; j++) {
        mnew[j] = fmaxf(m_run[j], rmax[j]);
        corr[j] = __expf(m_run[j] - mnew[j]);
      }
      m_run = mnew;
      f32x4 rs = (f32x4){0.f, 0.f, 0.f, 0.f};
#pragma unroll
      for (int ni = 0; ni < 4; ni++) {
#pragma unroll
        for (int j = 0; j < 4; j++) {
          float p = __expf(sc[ni][j] - mnew[j]);
          rs[j] += p;
          Ps[w * 16 + lg * 4 + j][ni * 16 + lr] = (bf16_t)p;
        }
      }
#pragma unroll
      for (int msk = 1; msk <= 8; msk <<= 1)
#pragma unroll
        for (int j = 0; j < 4; j++) rs[j] += __shfl_xor(rs[j], msk);
#pragma unroll
      for (int j = 0; j < 4; j++) l_run[j] = l_run[j] * corr[j] + rs[j];
#pragma unroll
      for (int nd = 0; nd < 4; nd++) o[nd] = o[nd] * corr;
    }

    // PV
#pragma unroll
    for (int kc = 0; kc < 2; kc++) {
      bf16x8 pa = *reinterpret_cast<const bf16x8*>(&Ps[w * 16 + lr][kc * 32 + lg * 8]);
      bf16x8 vb[4];
#pragma unroll
      for (int nd = 0; nd < 4; nd++)
        vb[nd] = *reinterpret_cast<const bf16x8*>(&Vs[buf][((nd << 1) + kc) * 512 + lane * 8]);
#pragma unroll
      for (int nd = 0; nd < 4; nd++)
        o[nd] = __builtin_amdgcn_mfma_f32_16x16x32_bf16(pa, vb[nd], o[nd], 0, 0, 0);
    }
    asm volatile("s_waitcnt vmcnt(0)" ::: "memory");
    asm volatile("s_barrier" ::: "memory");
  }

  f32x4 linv;
#pragma unroll
  for (int j = 0; j < 4; j++) linv[j] = 1.f / l_run[j];
#pragma unroll
  for (int nd = 0; nd < 4; nd++)
#pragma unroll
    for (int j = 0; j < 4; j++) {
      int rowg = b * SS + q0 + w * 16 + lg * 4 + j;
      int col = h * HD + nd * 16 + lr;
      ab[(size_t)rowg * EE + col] = (bf16_t)(o[nd][j] * linv[j]);
    }
}

extern "C" void kernel_launch(void* const* d_in, const int* in_sizes, int n_in,
                              void* d_out, int out_size, void* d_ws, size_t ws_size,
                              hipStream_t stream) {
  const int*   ids   = (const int*)d_in[0];
  const int*   amask = (const int*)d_in[1];
  const float* emb   = (const float*)d_in[2];
  const float* Wq    = (const float*)d_in[3];
  const float* Wk    = (const float*)d_in[4];
  const float* Wv    = (const float*)d_in[5];
  const float* Wo    = (const float*)d_in[6];
  const float* ln1g  = (const float*)d_in[7];
  const float* ln1b  = (const float*)d_in[8];
  const float* ln2g  = (const float*)d_in[9];
  const float* ln2b  = (const float*)d_in[10];
  const float* fw1   = (const float*)d_in[11];
  const float* fb1   = (const float*)d_in[12];
  const float* fw2   = (const float*)d_in[13];
  const float* fb2   = (const float*)d_in[14];
  const float* lnfg  = (const float*)d_in[15];
  const float* lnfb  = (const float*)d_in[16];
  const float* Wout  = (const float*)d_in[17];
  const float* bout  = (const float*)d_in[18];
  float* out = (float*)d_out;

  // ws: x (8MB) | xn (4MB) | WoutT (51.7MB padded to 50432 rows)
  float*  x     = (float*)d_ws;
  bf16_t* xn    = (bf16_t*)((char*)d_ws + (8u << 20));
  bf16_t* WoutT = (bf16_t*)((char*)d_ws + (12u << 20));
  // d_out head as scratch (57MB of 824MB; fully overwritten by final GEMM)
  char* sc = (char*)d_out;
  bf16_t* qbuf = (bf16_t*)(sc);
  bf16_t* kbuf = (bf16_t*)(sc + 4194304);
  bf16_t* vTb  = (bf16_t*)(sc + 8388608);
  bf16_t* ab   = (bf16_t*)(sc + 12582912);
  bf16_t* hb   = (bf16_t*)(sc + 16777216);
  bf16_t* Wqkv = (bf16_t*)(sc + 33554432);
  bf16_t* WoT  = (bf16_t*)(sc + 39845888);
  bf16_t* W1T  = (bf16_t*)(sc + 41943040);
  bf16_t* W2T  = (bf16_t*)(sc + 50331648);

  wconv_qkv_kernel<<<dim3(8, 1, 96), 256, 0, stream>>>(Wq, Wk, Wv, Wqkv);
  wconv_kernel<<<dim3(8, 8, LL), 256, 0, stream>>>(Wo, WoT, 512, 512, 512,
                                                   512L * 512, 512L * 512);
  wconv_kernel<<<dim3(8, 32, LL), 256, 0, stream>>>(fw1, W1T, 2048, 512, 2048,
                                                    512L * 2048, 2048L * 512);
  wconv_kernel<<<dim3(32, 8, LL), 256, 0, stream>>>(fw2, W2T, 512, 2048, 512,
                                                    2048L * 512, 512L * 2048);
  wconv_kernel<<<dim3(8, VPAD2 / 64, 1), 256, 0, stream>>>(Wout, WoutT, VV, 512, VV, 0, 0);

  embed_kernel<<<NTOK * EE / 256, 256, 0, stream>>>(ids, emb, x);

  for (int l = 0; l < LL; l++) {
    ln_kernel<<<NTOK / 4, 256, 0, stream>>>(x, xn, ln1g + l * EE, ln1b + l * EE);
    gemm_bf16<0, 128><<<dim3(12, 32), 256, 0, stream>>>(xn, Wqkv + (size_t)l * 1536 * 512,
        NTOK, 1536, 512, nullptr, nullptr, nullptr, qbuf, kbuf, vTb);
    attn_kernel<<<dim3(512), 256, 0, stream>>>(qbuf, kbuf, vTb, amask, ab);
    gemm_bf16<2, 64><<<dim3(4, 64), 256, 0, stream>>>(ab, WoT + (size_t)l * 512 * 512,
        NTOK, 512, 512, nullptr, x, nullptr, nullptr, nullptr, nullptr);
    ln_kernel<<<NTOK / 4, 256, 0, stream>>>(x, xn, ln2g + l * EE, ln2b + l * EE);
    gemm_bf16<1, 128><<<dim3(16, 32), 256, 0, stream>>>(xn, W1T + (size_t)l * 2048 * 512,
        NTOK, 2048, 512, fb1 + l * 2048, nullptr, hb, nullptr, nullptr, nullptr);
    gemm_bf16<2, 64><<<dim3(4, 64), 256, 0, stream>>>(hb, W2T + (size_t)l * 512 * 2048,
        NTOK, 512, 2048, fb2 + l * EE, x, nullptr, nullptr, nullptr, nullptr);
  }
  ln_kernel<<<NTOK / 4, 256, 0, stream>>>(x, xn, lnfg, lnfb);
  gemm256_out<<<dim3(16 * (VPAD2 / 256)), 512, 0, stream>>>(xn, WoutT, bout, out);
}

// Round 15
// 1293.624 us; speedup vs baseline: 1.4454x; 1.0533x over previous
//
#include <hip/hip_runtime.h>
#include <math.h>

#define BB 2
#define SS 2048
#define EE 512
#define HH 8
#define HD 64
#define LL 4
#define VV 50257
#define NTOK (BB*SS)
#define VPAD2 50432   // 197 * 256

typedef __bf16 bf16_t;
typedef bf16_t bf16x8 __attribute__((ext_vector_type(8)));
typedef float  f32x4  __attribute__((ext_vector_type(4)));

__device__ __forceinline__ void gload_lds16(const void* g, void* l) {
  __builtin_amdgcn_global_load_lds(
      (const __attribute__((address_space(1))) void*)g,
      (__attribute__((address_space(3))) void*)l, 16, 0, 0);
}

// ---------------- embedding + sinusoidal PE ----------------
__global__ __launch_bounds__(256) void embed_kernel(const int* __restrict__ ids,
                                                    const float* __restrict__ emb,
                                                    float* __restrict__ x) {
  int idx = blockIdx.x * 256 + threadIdx.x;
  int e   = idx & (EE - 1);
  int tok = idx >> 9;
  int s   = tok & (SS - 1);
  int id  = ids[tok];
  float freq = __expf((float)(e & ~1) * -0.01798894604f);
  float ang  = (float)s * freq;
  float pe   = (e & 1) ? __cosf(ang) : __sinf(ang);
  x[idx] = emb[(size_t)id * EE + e] + pe;
}

// ---------------- LayerNorm: fp32 in -> bf16 out, one wave per row ----------------
__global__ __launch_bounds__(256) void ln_kernel(const float* __restrict__ in,
                                                 bf16_t* __restrict__ out,
                                                 const float* __restrict__ g,
                                                 const float* __restrict__ b) {
  int wv = threadIdx.x >> 6, lane = threadIdx.x & 63;
  int row = blockIdx.x * 4 + wv;
  const float4* r = reinterpret_cast<const float4*>(in + (size_t)row * EE) + lane * 2;
  float4 v0 = r[0], v1 = r[1];
  float s = v0.x + v0.y + v0.z + v0.w + v1.x + v1.y + v1.z + v1.w;
#pragma unroll
  for (int o = 32; o > 0; o >>= 1) s += __shfl_xor(s, o);
  float mean = s * (1.f / EE);
  float d0 = v0.x-mean, d1 = v0.y-mean, d2 = v0.z-mean, d3 = v0.w-mean;
  float d4 = v1.x-mean, d5 = v1.y-mean, d6 = v1.z-mean, d7 = v1.w-mean;
  float var = d0*d0+d1*d1+d2*d2+d3*d3+d4*d4+d5*d5+d6*d6+d7*d7;
#pragma unroll
  for (int o = 32; o > 0; o >>= 1) var += __shfl_xor(var, o);
  float inv = rsqrtf(var * (1.f / EE) + 1e-5f);
  const float4* gp = reinterpret_cast<const float4*>(g) + lane * 2;
  const float4* bp = reinterpret_cast<const float4*>(b) + lane * 2;
  float4 g0 = gp[0], g1 = gp[1], b0 = bp[0], b1 = bp[1];
  bf16_t tmp[8];
  tmp[0] = (bf16_t)(d0*inv*g0.x + b0.x); tmp[1] = (bf16_t)(d1*inv*g0.y + b0.y);
  tmp[2] = (bf16_t)(d2*inv*g0.z + b0.z); tmp[3] = (bf16_t)(d3*inv*g0.w + b0.w);
  tmp[4] = (bf16_t)(d4*inv*g1.x + b1.x); tmp[5] = (bf16_t)(d5*inv*g1.y + b1.y);
  tmp[6] = (bf16_t)(d6*inv*g1.z + b1.z); tmp[7] = (bf16_t)(d7*inv*g1.w + b1.w);
  *reinterpret_cast<bf16x8*>(out + (size_t)row * EE + lane * 8) = *reinterpret_cast<bf16x8*>(tmp);
}

// ---------------- weight transpose+convert: fp32 [K][N] -> bf16 [N][K] ----------------
__device__ __forceinline__ void transpose_tile(const float* __restrict__ ip,
                                               bf16_t* __restrict__ op,
                                               int k0, int n0, int ldin, int ldout,
                                               int Nvalid, float* T) {
  int t = threadIdx.x;
  int r = t >> 2, cb = (t & 3) * 16;
#pragma unroll
  for (int i = 0; i < 16; i++) {
    int n = n0 + cb + i;
    T[r * 65 + cb + i] = (n < Nvalid) ? ip[(size_t)(k0 + r) * ldin + n] : 0.f;
  }
  __syncthreads();
  bf16_t tmp[16];
#pragma unroll
  for (int i = 0; i < 16; i++) tmp[i] = (bf16_t)T[(cb + i) * 65 + r];
  bf16_t* o = op + (size_t)(n0 + r) * ldout + k0 + cb;
  *reinterpret_cast<bf16x8*>(o)     = *reinterpret_cast<bf16x8*>(&tmp[0]);
  *reinterpret_cast<bf16x8*>(o + 8) = *reinterpret_cast<bf16x8*>(&tmp[8]);
}

__global__ __launch_bounds__(256) void wconv_kernel(const float* __restrict__ in,
                                                    bf16_t* __restrict__ out,
                                                    int ldin, int ldout, int Nvalid,
                                                    long zin, long zout) {
  __shared__ float T[64 * 65];
  transpose_tile(in + (size_t)blockIdx.z * zin, out + (size_t)blockIdx.z * zout,
                 blockIdx.x * 64, blockIdx.y * 64, ldin, ldout, Nvalid, T);
}

__global__ __launch_bounds__(256) void wconv_qkv_kernel(const float* __restrict__ Wq,
                                                        const float* __restrict__ Wk,
                                                        const float* __restrict__ Wv,
                                                        bf16_t* __restrict__ out) {
  __shared__ float T[64 * 65];
  int z = blockIdx.z;
  int l = z / 24, rem = z % 24, sec = rem >> 3, h = rem & 7;
  const float* W = sec == 0 ? Wq : (sec == 1 ? Wk : Wv);
  const float* ip = W + (size_t)(l * 8 + h) * (EE * HD);
  bf16_t* op = out + (size_t)l * (1536 * 512) + (size_t)(sec * 512 + h * 64) * 512;
  transpose_tile(ip, op, blockIdx.x * 64, 0, HD, EE, HD, T);
}

// ---------------- layer GEMMs: 2-phase counted-vmcnt dbuf ----
// MODE: 0=QKV scatter, 1=bias+GELU->bf16, 2=(+bias)+residual f32.
template<int MODE, int TM>
__global__ __launch_bounds__(256) void gemm_bf16(
    const bf16_t* __restrict__ A, const bf16_t* __restrict__ Bt,
    int M, int N, int K,
    const float* __restrict__ bias,
    float* __restrict__ Cf, bf16_t* __restrict__ Cb,
    bf16_t* __restrict__ qo, bf16_t* __restrict__ ko, bf16_t* __restrict__ vo) {
  constexpr int MI = TM / 32;
  constexpr int LW = MI + 4;
  __shared__ __align__(16) bf16_t As[2][TM * 64];
  __shared__ __align__(16) bf16_t Bs[2][128 * 64];
  int tid = threadIdx.x, lane = tid & 63, w = tid >> 6;
  int lr = lane & 15, lg = lane >> 4;
  int m0 = blockIdx.y * TM, n0 = blockIdx.x * 128;
  f32x4 acc[MI][4];
#pragma unroll
  for (int i = 0; i < MI; i++)
#pragma unroll
    for (int j = 0; j < 4; j++) acc[i][j] = (f32x4){0.f, 0.f, 0.f, 0.f};
  int wr = w >> 1, wc = w & 1;

  const bf16_t* Abase = A  + (size_t)(m0 + lr) * K + lg * 8;
  const bf16_t* Bbase = Bt + (size_t)(n0 + lr) * K + lg * 8;

  auto stage = [&](int buf, int k0) {
#pragma unroll
    for (int i = 0; i < MI; i++) {
      int c = w * MI + i;
      gload_lds16(Abase + (size_t)(c >> 1) * 16 * K + k0 + (c & 1) * 32,
                  (char*)&As[buf][0] + c * 1024);
    }
#pragma unroll
    for (int i = 0; i < 4; i++) {
      int c = w * 4 + i;
      gload_lds16(Bbase + (size_t)(c >> 1) * 16 * K + k0 + (c & 1) * 32,
                  (char*)&Bs[buf][0] + c * 1024);
    }
  };

  int nk = K >> 6;
  stage(0, 0);
  for (int k = 0; k < nk; k++) {
    int cur = k & 1;
    if (k + 1 < nk) {
      stage(cur ^ 1, (k + 1) << 6);
      asm volatile("s_waitcnt vmcnt(%0)" :: "i"(LW) : "memory");
    } else {
      asm volatile("s_waitcnt vmcnt(0)" ::: "memory");
    }
    __builtin_amdgcn_s_barrier();
#pragma unroll
    for (int kk = 0; kk < 2; kk++) {
      bf16x8 afr[MI], bfr[4];
#pragma unroll
      for (int mi = 0; mi < MI; mi++)
        afr[mi] = *reinterpret_cast<const bf16x8*>(
            &As[cur][(((wr * MI + mi) << 1) + kk) * 512 + lane * 8]);
#pragma unroll
      for (int ni = 0; ni < 4; ni++)
        bfr[ni] = *reinterpret_cast<const bf16x8*>(
            &Bs[cur][(((wc * 4 + ni) << 1) + kk) * 512 + lane * 8]);
#pragma unroll
      for (int mi = 0; mi < MI; mi++)
#pragma unroll
        for (int ni = 0; ni < 4; ni++)
          acc[mi][ni] = __builtin_amdgcn_mfma_f32_16x16x32_bf16(afr[mi], bfr[ni], acc[mi][ni], 0, 0, 0);
    }
    __builtin_amdgcn_s_barrier();
  }

#pragma unroll
  for (int mi = 0; mi < MI; mi++)
#pragma unroll
    for (int ni = 0; ni < 4; ni++) {
      int colg = n0 + wc * 64 + ni * 16 + lr;
#pragma unroll
      for (int j = 0; j < 4; j++) {
        int rowg = m0 + wr * (TM / 2) + mi * 16 + lg * 4 + j;
        float v = acc[mi][ni][j];
        if (MODE == 0) {
          int sec = colg >> 9, cc = colg & 511, hh = cc >> 6, dd = cc & 63;
          int bi = rowg >> 11, s = rowg & 2047;
          if (sec == 0)      qo[(((size_t)bi * HH + hh) * SS + s) * HD + dd] = (bf16_t)(v * 0.125f);
          else if (sec == 1) ko[(((size_t)bi * HH + hh) * SS + s) * HD + dd] = (bf16_t)v;
          else               vo[(((size_t)bi * HH + hh) * HD + dd) * SS + s] = (bf16_t)v;
        } else if (MODE == 1) {
          v += bias[colg];
          v = 0.5f * v * (1.f + erff(v * 0.70710678f));
          Cb[(size_t)rowg * N + colg] = (bf16_t)v;
        } else {
          if (bias) v += bias[colg];
          Cf[(size_t)rowg * EE + colg] += v;
        }
      }
    }
}

// ---------------- vocab GEMM: 256², single-buffer, N-fastest ------------------
// LDS-transposed epilogue -> 1KB-contiguous-per-wave NONTEMPORAL stores.
__global__ __launch_bounds__(512) void gemm256_out(
    const bf16_t* __restrict__ A, const bf16_t* __restrict__ Bt,
    const float* __restrict__ bias, float* __restrict__ C) {
  __shared__ __align__(16) char smem[64 * 260 * 4];   // 66560 B
  bf16_t* As = (bf16_t*)smem;
  bf16_t* Bs = (bf16_t*)(smem + 32768);
  float*  Ep = (float*)smem;
  int tid = threadIdx.x, lane = tid & 63, w = tid >> 6;
  int lr = lane & 15, lg = lane >> 4;
  int bid = blockIdx.x;
  int n0 = (bid % 197) * 256, m0 = (bid / 197) * 256;
  int wr = w >> 2, wc = w & 3;
  f32x4 acc[8][4];
#pragma unroll
  for (int i = 0; i < 8; i++)
#pragma unroll
    for (int j = 0; j < 4; j++) acc[i][j] = (f32x4){0.f, 0.f, 0.f, 0.f};

  const bf16_t* Abase = A  + (size_t)(m0 + lr) * 512 + lg * 8;
  const bf16_t* Bbase = Bt + (size_t)(n0 + lr) * 512 + lg * 8;

  for (int k0 = 0; k0 < 512; k0 += 64) {
#pragma unroll
    for (int i = 0; i < 4; i++) {
      int c = w * 4 + i;
      gload_lds16(Abase + (size_t)(c >> 1) * 16 * 512 + k0 + (c & 1) * 32,
                  (char*)As + c * 1024);
      gload_lds16(Bbase + (size_t)(c >> 1) * 16 * 512 + k0 + (c & 1) * 32,
                  (char*)Bs + c * 1024);
    }
    __syncthreads();
#pragma unroll
    for (int kk = 0; kk < 2; kk++) {
      bf16x8 afr[8], bfr[4];
#pragma unroll
      for (int mi = 0; mi < 8; mi++)
        afr[mi] = *reinterpret_cast<const bf16x8*>(
            &As[(((wr * 8 + mi) << 1) + kk) * 512 + lane * 8]);
#pragma unroll
      for (int ni = 0; ni < 4; ni++)
        bfr[ni] = *reinterpret_cast<const bf16x8*>(
            &Bs[(((wc * 4 + ni) << 1) + kk) * 512 + lane * 8]);
#pragma unroll
      for (int mi = 0; mi < 8; mi++)
#pragma unroll
        for (int ni = 0; ni < 4; ni++)
          acc[mi][ni] = __builtin_amdgcn_mfma_f32_16x16x32_bf16(afr[mi], bfr[ni], acc[mi][ni], 0, 0, 0);
    }
    __syncthreads();
  }

  // epilogue: 4 chunks of 64 rows via LDS; coalesced NT f32x4 stores
  int colBase = n0 + (tid & 63) * 4;
  float b0 = 0.f, b1 = 0.f, b2 = 0.f, b3 = 0.f;
  if (colBase + 3 < VV) {
    float4 bv = *reinterpret_cast<const float4*>(bias + colBase);
    b0 = bv.x; b1 = bv.y; b2 = bv.z; b3 = bv.w;
  } else {
    if (colBase     < VV) b0 = bias[colBase];
    if (colBase + 1 < VV) b1 = bias[colBase + 1];
    if (colBase + 2 < VV) b2 = bias[colBase + 2];
  }
  int rw = tid >> 6;
  for (int ch = 0; ch < 4; ch++) {
    __syncthreads();
    if (wr == (ch >> 1)) {
      int mib = (ch & 1) * 4;
#pragma unroll
      for (int mi2 = 0; mi2 < 4; mi2++)
#pragma unroll
        for (int ni = 0; ni < 4; ni++) {
          int col = wc * 64 + ni * 16 + lr;
#pragma unroll
          for (int j = 0; j < 4; j++)
            Ep[(mi2 * 16 + lg * 4 + j) * 260 + col] = acc[mib + mi2][ni][j];
        }
    }
    __syncthreads();
#pragma unroll
    for (int pass = 0; pass < 8; pass++) {
      int r = pass * 8 + rw;
      f32x4 v = *reinterpret_cast<const f32x4*>(&Ep[r * 260 + (tid & 63) * 4]);
      v[0] += b0; v[1] += b1; v[2] += b2; v[3] += b3;
      float* dst = &C[(size_t)(m0 + ch * 64 + r) * VV + colBase];
      if (colBase + 3 < VV) {
        __builtin_nontemporal_store(v, reinterpret_cast<f32x4*>(dst));
      } else {
        if (colBase     < VV) __builtin_nontemporal_store(v[0], dst);
        if (colBase + 1 < VV) __builtin_nontemporal_store(v[1], dst + 1);
        if (colBase + 2 < VV) __builtin_nontemporal_store(v[2], dst + 2);
      }
    }
  }
}

// ---------------- flash attention v3: QBLK=64, load-balanced, 2 blocks/CU ----
#define QBLK 64
#define KVB 64
__global__ __launch_bounds__(256) void attn_kernel(
    const bf16_t* __restrict__ qb, const bf16_t* __restrict__ kb,
    const bf16_t* __restrict__ vT, const int* __restrict__ amask,
    bf16_t* __restrict__ ab) {
  __shared__ bf16_t Qs[QBLK][72];
  __shared__ bf16_t Ps[QBLK][72];
  __shared__ __align__(16) bf16_t Ks[2][KVB * 64];
  __shared__ __align__(16) bf16_t Vs[2][KVB * 64];
  __shared__ float kmAll[SS];
  int tid = threadIdx.x, lane = tid & 63, w = tid >> 6;
  int lr = lane & 15, lg = lane >> 4;
  int bid = blockIdx.x;
  int bh = bid & 15;
  int qi = bid >> 4;
  int qq = (qi < 16) ? qi : 47 - qi;
  int q0 = qq * QBLK;
  int b = bh >> 3, h = bh & 7;
  const bf16_t* Qg = qb + (size_t)bh * SS * HD;
  const bf16_t* Kg = kb + (size_t)bh * SS * HD;
  const bf16_t* Vg = vT + (size_t)bh * HD * SS;

  {
    int r = tid >> 2, c = (tid & 3) * 16;
    const uint4* s = reinterpret_cast<const uint4*>(Qg + (size_t)(q0 + r) * HD + c);
    uint4 a0 = s[0], a1 = s[1];
    *reinterpret_cast<uint4*>(&Qs[r][c])     = a0;
    *reinterpret_cast<uint4*>(&Qs[r][c + 8]) = a1;
  }
#pragma unroll
  for (int i = 0; i < 8; i++) {
    int s = i * 256 + tid;
    kmAll[s] = amask[b * SS + s] ? 0.f : -1e30f;
  }

  auto stageKV = [&](int buf, int kv0) {
#pragma unroll
    for (int i = 0; i < 4; i++) {
      int c = w * 4 + i;
      if (c < 8) {
        gload_lds16(Kg + (size_t)(kv0 + (c >> 1) * 16 + lr) * HD + (c & 1) * 32 + lg * 8,
                    (char*)&Ks[buf][0] + c * 1024);
      } else {
        int cc = c - 8;
        gload_lds16(Vg + (size_t)((cc >> 1) * 16 + lr) * SS + kv0 + (cc & 1) * 32 + lg * 8,
                    (char*)&Vs[buf][0] + cc * 1024);
      }
    }
  };

  f32x4 o[4];
  f32x4 m_run, l_run;
  m_run = (f32x4){-1e30f, -1e30f, -1e30f, -1e30f};
  l_run = (f32x4){0.f, 0.f, 0.f, 0.f};
#pragma unroll
  for (int nd = 0; nd < 4; nd++) o[nd] = (f32x4){0.f, 0.f, 0.f, 0.f};

  stageKV(0, 0);
  __syncthreads();

  int ntile = qq + 1;
  for (int t = 0; t < ntile; t++) {
    int buf = t & 1;
    int kv0 = t * KVB;
    if (t + 1 < ntile) stageKV(buf ^ 1, kv0 + KVB);

    f32x4 sc[4];
#pragma unroll
    for (int ni = 0; ni < 4; ni++) sc[ni] = (f32x4){0.f, 0.f, 0.f, 0.f};
#pragma unroll
    for (int kk = 0; kk < 2; kk++) {
      bf16x8 af = *reinterpret_cast<const bf16x8*>(&Qs[w * 16 + lr][kk * 32 + lg * 8]);
      bf16x8 bf[4];
#pragma unroll
      for (int ni = 0; ni < 4; ni++)
        bf[ni] = *reinterpret_cast<const bf16x8*>(&Ks[buf][((ni << 1) + kk) * 512 + lane * 8]);
#pragma unroll
      for (int ni = 0; ni < 4; ni++)
        sc[ni] = __builtin_amdgcn_mfma_f32_16x16x32_bf16(af, bf[ni], sc[ni], 0, 0, 0);
    }

    {
      int qrb = q0 + w * 16 + lg * 4;
      float kmv[4];
#pragma unroll
      for (int ni = 0; ni < 4; ni++) kmv[ni] = kmAll[kv0 + ni * 16 + lr];
#pragma unroll
      for (int ni = 0; ni < 4; ni++) {
        int kg = kv0 + ni * 16 + lr;
#pragma unroll
        for (int j = 0; j < 4; j++) {
          float s = sc[ni][j] + kmv[ni];
          sc[ni][j] = (kg <= qrb + j) ? s : -1e30f;
        }
      }
      f32x4 rmax = sc[0];
#pragma unroll
      for (int ni = 1; ni < 4; ni++)
#pragma unroll
        for (int j = 0; j < 4; j++) rmax[j] = fmaxf(rmax[j], sc[ni][j]);
#pragma unroll
      for (int msk = 1; msk <= 8; msk <<= 1)
#pragma unroll
        for (int j = 0; j < 4; j++) rmax[j] = fmaxf(rmax[j], __shfl_xor(rmax[j], msk));
      f32x4 mnew, corr;
#pragma unroll
      for (int j = 0; j < 4; j++) {
        mnew[j] = fmaxf(m_run[j], rmax[j]);
        corr[j] = __expf(m_run[j] - mnew[j]);
      }
      m_run = mnew;
      f32x4 rs = (f32x4){0.f, 0.f, 0.f, 0.f};
#pragma unroll
      for (int ni = 0; ni < 4; ni++) {
#pragma unroll
        for (int j = 0; j < 4; j++) {
          float p = __expf(sc[ni][j] - mnew[j]);
          rs[j] += p;
          Ps[w * 16 + lg * 4 + j][ni * 16 + lr] = (bf16_t)p;
        }
      }
#pragma unroll
      for (int msk = 1; msk <= 8; msk <<= 1)
#pragma unroll
        for (int j = 0; j < 4; j++) rs[j] += __shfl_xor(rs[j], msk);
#pragma unroll
      for (int j = 0; j < 4; j++) l_run[j] = l_run[j] * corr[j] + rs[j];
#pragma unroll
      for (int nd = 0; nd < 4; nd++) o[nd] = o[nd] * corr;
    }

#pragma unroll
    for (int kc = 0; kc < 2; kc++) {
      bf16x8 pa = *reinterpret_cast<const bf16x8*>(&Ps[w * 16 + lr][kc * 32 + lg * 8]);
      bf16x8 vb[4];
#pragma unroll
      for (int nd = 0; nd < 4; nd++)
        vb[nd] = *reinterpret_cast<const bf16x8*>(&Vs[buf][((nd << 1) + kc) * 512 + lane * 8]);
#pragma unroll
      for (int nd = 0; nd < 4; nd++)
        o[nd] = __builtin_amdgcn_mfma_f32_16x16x32_bf16(pa, vb[nd], o[nd], 0, 0, 0);
    }
    asm volatile("s_waitcnt vmcnt(0)" ::: "memory");
    asm volatile("s_barrier" ::: "memory");
  }

  f32x4 linv;
#pragma unroll
  for (int j = 0; j < 4; j++) linv[j] = 1.f / l_run[j];
#pragma unroll
  for (int nd = 0; nd < 4; nd++)
#pragma unroll
    for (int j = 0; j < 4; j++) {
      int rowg = b * SS + q0 + w * 16 + lg * 4 + j;
      int col = h * HD + nd * 16 + lr;
      ab[(size_t)rowg * EE + col] = (bf16_t)(o[nd][j] * linv[j]);
    }
}

extern "C" void kernel_launch(void* const* d_in, const int* in_sizes, int n_in,
                              void* d_out, int out_size, void* d_ws, size_t ws_size,
                              hipStream_t stream) {
  const int*   ids   = (const int*)d_in[0];
  const int*   amask = (const int*)d_in[1];
  const float* emb   = (const float*)d_in[2];
  const float* Wq    = (const float*)d_in[3];
  const float* Wk    = (const float*)d_in[4];
  const float* Wv    = (const float*)d_in[5];
  const float* Wo    = (const float*)d_in[6];
  const float* ln1g  = (const float*)d_in[7];
  const float* ln1b  = (const float*)d_in[8];
  const float* ln2g  = (const float*)d_in[9];
  const float* ln2b  = (const float*)d_in[10];
  const float* fw1   = (const float*)d_in[11];
  const float* fb1   = (const float*)d_in[12];
  const float* fw2   = (const float*)d_in[13];
  const float* fb2   = (const float*)d_in[14];
  const float* lnfg  = (const float*)d_in[15];
  const float* lnfb  = (const float*)d_in[16];
  const float* Wout  = (const float*)d_in[17];
  const float* bout  = (const float*)d_in[18];
  float* out = (float*)d_out;

  float*  x     = (float*)d_ws;
  bf16_t* xn    = (bf16_t*)((char*)d_ws + (8u << 20));
  bf16_t* WoutT = (bf16_t*)((char*)d_ws + (12u << 20));
  char* sc = (char*)d_out;
  bf16_t* qbuf = (bf16_t*)(sc);
  bf16_t* kbuf = (bf16_t*)(sc + 4194304);
  bf16_t* vTb  = (bf16_t*)(sc + 8388608);
  bf16_t* ab   = (bf16_t*)(sc + 12582912);
  bf16_t* hb   = (bf16_t*)(sc + 16777216);
  bf16_t* Wqkv = (bf16_t*)(sc + 33554432);
  bf16_t* WoT  = (bf16_t*)(sc + 39845888);
  bf16_t* W1T  = (bf16_t*)(sc + 41943040);
  bf16_t* W2T  = (bf16_t*)(sc + 50331648);

  wconv_qkv_kernel<<<dim3(8, 1, 96), 256, 0, stream>>>(Wq, Wk, Wv, Wqkv);
  wconv_kernel<<<dim3(8, 8, LL), 256, 0, stream>>>(Wo, WoT, 512, 512, 512,
                                                   512L * 512, 512L * 512);
  wconv_kernel<<<dim3(8, 32, LL), 256, 0, stream>>>(fw1, W1T, 2048, 512, 2048,
                                                    512L * 2048, 2048L * 512);
  wconv_kernel<<<dim3(32, 8, LL), 256, 0, stream>>>(fw2, W2T, 512, 2048, 512,
                                                    2048L * 512, 512L * 2048);
  wconv_kernel<<<dim3(8, VPAD2 / 64, 1), 256, 0, stream>>>(Wout, WoutT, VV, 512, VV, 0, 0);

  embed_kernel<<<NTOK * EE / 256, 256, 0, stream>>>(ids, emb, x);

  for (int l = 0; l < LL; l++) {
    ln_kernel<<<NTOK / 4, 256, 0, stream>>>(x, xn, ln1g + l * EE, ln1b + l * EE);
    gemm_bf16<0, 128><<<dim3(12, 32), 256, 0, stream>>>(xn, Wqkv + (size_t)l * 1536 * 512,
        NTOK, 1536, 512, nullptr, nullptr, nullptr, qbuf, kbuf, vTb);
    attn_kernel<<<dim3(512), 256, 0, stream>>>(qbuf, kbuf, vTb, amask, ab);
    gemm_bf16<2, 64><<<dim3(4, 64), 256, 0, stream>>>(ab, WoT + (size_t)l * 512 * 512,
        NTOK, 512, 512, nullptr, x, nullptr, nullptr, nullptr, nullptr);
    ln_kernel<<<NTOK / 4, 256, 0, stream>>>(x, xn, ln2g + l * EE, ln2b + l * EE);
    gemm_bf16<1, 128><<<dim3(16, 32), 256, 0, stream>>>(xn, W1T + (size_t)l * 2048 * 512,
        NTOK, 2048, 512, fb1 + l * 2048, nullptr, hb, nullptr, nullptr, nullptr);
    gemm_bf16<2, 64><<<dim3(4, 64), 256, 0, stream>>>(hb, W2T + (size_t)l * 512 * 2048,
        NTOK, 512, 2048, fb2 + l * EE, x, nullptr, nullptr, nullptr, nullptr);
  }
  ln_kernel<<<NTOK / 4, 256, 0, stream>>>(x, xn, lnfg, lnfb);
  gemm256_out<<<dim3(16 * (VPAD2 / 256)), 512, 0, stream>>>(xn, WoutT, bout, out);
}

// Round 16
// 1281.061 us; speedup vs baseline: 1.4596x; 1.0098x over previous
//
#include <hip/hip_runtime.h>
#include <math.h>

#define BB 2
#define SS 2048
#define EE 512
#define HH 8
#define HD 64
#define LL 4
#define VV 50257
#define NTOK (BB*SS)
#define VPAD2 50432   // 197 * 256

typedef __bf16 bf16_t;
typedef bf16_t bf16x8 __attribute__((ext_vector_type(8)));
typedef float  f32x4  __attribute__((ext_vector_type(4)));

__device__ __forceinline__ void gload_lds16(const void* g, void* l) {
  __builtin_amdgcn_global_load_lds(
      (const __attribute__((address_space(1))) void*)g,
      (__attribute__((address_space(3))) void*)l, 16, 0, 0);
}

// ---------------- embedding + sinusoidal PE ----------------
__global__ __launch_bounds__(256) void embed_kernel(const int* __restrict__ ids,
                                                    const float* __restrict__ emb,
                                                    float* __restrict__ x) {
  int idx = blockIdx.x * 256 + threadIdx.x;
  int e   = idx & (EE - 1);
  int tok = idx >> 9;
  int s   = tok & (SS - 1);
  int id  = ids[tok];
  float freq = __expf((float)(e & ~1) * -0.01798894604f);
  float ang  = (float)s * freq;
  float pe   = (e & 1) ? __cosf(ang) : __sinf(ang);
  x[idx] = emb[(size_t)id * EE + e] + pe;
}

// ---------------- LayerNorm: fp32 in -> bf16 out, one wave per row ----------------
__global__ __launch_bounds__(256) void ln_kernel(const float* __restrict__ in,
                                                 bf16_t* __restrict__ out,
                                                 const float* __restrict__ g,
                                                 const float* __restrict__ b) {
  int wv = threadIdx.x >> 6, lane = threadIdx.x & 63;
  int row = blockIdx.x * 4 + wv;
  const float4* r = reinterpret_cast<const float4*>(in + (size_t)row * EE) + lane * 2;
  float4 v0 = r[0], v1 = r[1];
  float s = v0.x + v0.y + v0.z + v0.w + v1.x + v1.y + v1.z + v1.w;
#pragma unroll
  for (int o = 32; o > 0; o >>= 1) s += __shfl_xor(s, o);
  float mean = s * (1.f / EE);
  float d0 = v0.x-mean, d1 = v0.y-mean, d2 = v0.z-mean, d3 = v0.w-mean;
  float d4 = v1.x-mean, d5 = v1.y-mean, d6 = v1.z-mean, d7 = v1.w-mean;
  float var = d0*d0+d1*d1+d2*d2+d3*d3+d4*d4+d5*d5+d6*d6+d7*d7;
#pragma unroll
  for (int o = 32; o > 0; o >>= 1) var += __shfl_xor(var, o);
  float inv = rsqrtf(var * (1.f / EE) + 1e-5f);
  const float4* gp = reinterpret_cast<const float4*>(g) + lane * 2;
  const float4* bp = reinterpret_cast<const float4*>(b) + lane * 2;
  float4 g0 = gp[0], g1 = gp[1], b0 = bp[0], b1 = bp[1];
  bf16_t tmp[8];
  tmp[0] = (bf16_t)(d0*inv*g0.x + b0.x); tmp[1] = (bf16_t)(d1*inv*g0.y + b0.y);
  tmp[2] = (bf16_t)(d2*inv*g0.z + b0.z); tmp[3] = (bf16_t)(d3*inv*g0.w + b0.w);
  tmp[4] = (bf16_t)(d4*inv*g1.x + b1.x); tmp[5] = (bf16_t)(d5*inv*g1.y + b1.y);
  tmp[6] = (bf16_t)(d6*inv*g1.z + b1.z); tmp[7] = (bf16_t)(d7*inv*g1.w + b1.w);
  *reinterpret_cast<bf16x8*>(out + (size_t)row * EE + lane * 8) = *reinterpret_cast<bf16x8*>(tmp);
}

// ---------------- weight transpose+convert: fp32 [K][N] -> bf16 [N][K] ----------------
__device__ __forceinline__ void transpose_tile(const float* __restrict__ ip,
                                               bf16_t* __restrict__ op,
                                               int k0, int n0, int ldin, int ldout,
                                               int Nvalid, float* T) {
  int t = threadIdx.x;
  int r = t >> 2, cb = (t & 3) * 16;
#pragma unroll
  for (int i = 0; i < 16; i++) {
    int n = n0 + cb + i;
    T[r * 65 + cb + i] = (n < Nvalid) ? ip[(size_t)(k0 + r) * ldin + n] : 0.f;
  }
  __syncthreads();
  bf16_t tmp[16];
#pragma unroll
  for (int i = 0; i < 16; i++) tmp[i] = (bf16_t)T[(cb + i) * 65 + r];
  bf16_t* o = op + (size_t)(n0 + r) * ldout + k0 + cb;
  *reinterpret_cast<bf16x8*>(o)     = *reinterpret_cast<bf16x8*>(&tmp[0]);
  *reinterpret_cast<bf16x8*>(o + 8) = *reinterpret_cast<bf16x8*>(&tmp[8]);
}

__global__ __launch_bounds__(256) void wconv_kernel(const float* __restrict__ in,
                                                    bf16_t* __restrict__ out,
                                                    int ldin, int ldout, int Nvalid,
                                                    long zin, long zout) {
  __shared__ float T[64 * 65];
  transpose_tile(in + (size_t)blockIdx.z * zin, out + (size_t)blockIdx.z * zout,
                 blockIdx.x * 64, blockIdx.y * 64, ldin, ldout, Nvalid, T);
}

__global__ __launch_bounds__(256) void wconv_qkv_kernel(const float* __restrict__ Wq,
                                                        const float* __restrict__ Wk,
                                                        const float* __restrict__ Wv,
                                                        bf16_t* __restrict__ out) {
  __shared__ float T[64 * 65];
  int z = blockIdx.z;
  int l = z / 24, rem = z % 24, sec = rem >> 3, h = rem & 7;
  const float* W = sec == 0 ? Wq : (sec == 1 ? Wk : Wv);
  const float* ip = W + (size_t)(l * 8 + h) * (EE * HD);
  bf16_t* op = out + (size_t)l * (1536 * 512) + (size_t)(sec * 512 + h * 64) * 512;
  transpose_tile(ip, op, blockIdx.x * 64, 0, HD, EE, HD, T);
}

// ---------------- layer GEMMs: 2-phase counted-vmcnt dbuf, fragment-major ----
// TM in {32,64,128}. MODE: 0=QKV scatter, 1=bias+GELU->bf16, 2=(+bias)+resid f32.
template<int MODE, int TM>
__global__ __launch_bounds__(256) void gemm_bf16(
    const bf16_t* __restrict__ A, const bf16_t* __restrict__ Bt,
    int M, int N, int K,
    const float* __restrict__ bias,
    float* __restrict__ Cf, bf16_t* __restrict__ Cb,
    bf16_t* __restrict__ qo, bf16_t* __restrict__ ko, bf16_t* __restrict__ vo) {
  constexpr int MI = TM / 32;                 // acc rows per wave (1/2/4)
  constexpr int LW = MI + 4;                  // loads/wave/stage
  __shared__ __align__(16) bf16_t As[2][TM * 64];
  __shared__ __align__(16) bf16_t Bs[2][128 * 64];
  int tid = threadIdx.x, lane = tid & 63, w = tid >> 6;
  int lr = lane & 15, lg = lane >> 4;
  int m0 = blockIdx.y * TM, n0 = blockIdx.x * 128;
  f32x4 acc[MI][4];
#pragma unroll
  for (int i = 0; i < MI; i++)
#pragma unroll
    for (int j = 0; j < 4; j++) acc[i][j] = (f32x4){0.f, 0.f, 0.f, 0.f};
  int wr = w >> 1, wc = w & 1;

  const bf16_t* Abase = A  + (size_t)(m0 + lr) * K + lg * 8;
  const bf16_t* Bbase = Bt + (size_t)(n0 + lr) * K + lg * 8;

  auto stage = [&](int buf, int k0) {
#pragma unroll
    for (int i = 0; i < MI; i++) {
      int c = w * MI + i;
      gload_lds16(Abase + (size_t)(c >> 1) * 16 * K + k0 + (c & 1) * 32,
                  (char*)&As[buf][0] + c * 1024);
    }
#pragma unroll
    for (int i = 0; i < 4; i++) {
      int c = w * 4 + i;
      gload_lds16(Bbase + (size_t)(c >> 1) * 16 * K + k0 + (c & 1) * 32,
                  (char*)&Bs[buf][0] + c * 1024);
    }
  };

  int nk = K >> 6;
  stage(0, 0);
  for (int k = 0; k < nk; k++) {
    int cur = k & 1;
    if (k + 1 < nk) {
      stage(cur ^ 1, (k + 1) << 6);
      asm volatile("s_waitcnt vmcnt(%0)" :: "i"(LW) : "memory");
    } else {
      asm volatile("s_waitcnt vmcnt(0)" ::: "memory");
    }
    __builtin_amdgcn_s_barrier();
    __builtin_amdgcn_s_setprio(1);
#pragma unroll
    for (int kk = 0; kk < 2; kk++) {
      bf16x8 afr[MI], bfr[4];
#pragma unroll
      for (int mi = 0; mi < MI; mi++)
        afr[mi] = *reinterpret_cast<const bf16x8*>(
            &As[cur][(((wr * MI + mi) << 1) + kk) * 512 + lane * 8]);
#pragma unroll
      for (int ni = 0; ni < 4; ni++)
        bfr[ni] = *reinterpret_cast<const bf16x8*>(
            &Bs[cur][(((wc * 4 + ni) << 1) + kk) * 512 + lane * 8]);
#pragma unroll
      for (int mi = 0; mi < MI; mi++)
#pragma unroll
        for (int ni = 0; ni < 4; ni++)
          acc[mi][ni] = __builtin_amdgcn_mfma_f32_16x16x32_bf16(afr[mi], bfr[ni], acc[mi][ni], 0, 0, 0);
    }
    __builtin_amdgcn_s_setprio(0);
    __builtin_amdgcn_s_barrier();
  }

#pragma unroll
  for (int mi = 0; mi < MI; mi++)
#pragma unroll
    for (int ni = 0; ni < 4; ni++) {
      int colg = n0 + wc * 64 + ni * 16 + lr;
#pragma unroll
      for (int j = 0; j < 4; j++) {
        int rowg = m0 + wr * (TM / 2) + mi * 16 + lg * 4 + j;
        float v = acc[mi][ni][j];
        if (MODE == 0) {
          int sec = colg >> 9, cc = colg & 511, hh = cc >> 6, dd = cc & 63;
          int bi = rowg >> 11, s = rowg & 2047;
          if (sec == 0)      qo[(((size_t)bi * HH + hh) * SS + s) * HD + dd] = (bf16_t)(v * 0.125f);
          else if (sec == 1) ko[(((size_t)bi * HH + hh) * SS + s) * HD + dd] = (bf16_t)v;
          else               vo[(((size_t)bi * HH + hh) * HD + dd) * SS + s] = (bf16_t)v;
        } else if (MODE == 1) {
          v += bias[colg];
          v = 0.5f * v * (1.f + erff(v * 0.70710678f));
          Cb[(size_t)rowg * N + colg] = (bf16_t)v;
        } else {
          if (bias) v += bias[colg];
          Cf[(size_t)rowg * EE + colg] += v;
        }
      }
    }
}

// ---------------- vocab GEMM: 256², single-buffer, N-fastest, NT epilogue ----
__global__ __launch_bounds__(512) void gemm256_out(
    const bf16_t* __restrict__ A, const bf16_t* __restrict__ Bt,
    const float* __restrict__ bias, float* __restrict__ C) {
  __shared__ __align__(16) char smem[64 * 260 * 4];   // 66560 B
  bf16_t* As = (bf16_t*)smem;
  bf16_t* Bs = (bf16_t*)(smem + 32768);
  float*  Ep = (float*)smem;
  int tid = threadIdx.x, lane = tid & 63, w = tid >> 6;
  int lr = lane & 15, lg = lane >> 4;
  int bid = blockIdx.x;
  int n0 = (bid % 197) * 256, m0 = (bid / 197) * 256;
  int wr = w >> 2, wc = w & 3;
  f32x4 acc[8][4];
#pragma unroll
  for (int i = 0; i < 8; i++)
#pragma unroll
    for (int j = 0; j < 4; j++) acc[i][j] = (f32x4){0.f, 0.f, 0.f, 0.f};

  const bf16_t* Abase = A  + (size_t)(m0 + lr) * 512 + lg * 8;
  const bf16_t* Bbase = Bt + (size_t)(n0 + lr) * 512 + lg * 8;

  for (int k0 = 0; k0 < 512; k0 += 64) {
#pragma unroll
    for (int i = 0; i < 4; i++) {
      int c = w * 4 + i;
      gload_lds16(Abase + (size_t)(c >> 1) * 16 * 512 + k0 + (c & 1) * 32,
                  (char*)As + c * 1024);
      gload_lds16(Bbase + (size_t)(c >> 1) * 16 * 512 + k0 + (c & 1) * 32,
                  (char*)Bs + c * 1024);
    }
    __syncthreads();
#pragma unroll
    for (int kk = 0; kk < 2; kk++) {
      bf16x8 afr[8], bfr[4];
#pragma unroll
      for (int mi = 0; mi < 8; mi++)
        afr[mi] = *reinterpret_cast<const bf16x8*>(
            &As[(((wr * 8 + mi) << 1) + kk) * 512 + lane * 8]);
#pragma unroll
      for (int ni = 0; ni < 4; ni++)
        bfr[ni] = *reinterpret_cast<const bf16x8*>(
            &Bs[(((wc * 4 + ni) << 1) + kk) * 512 + lane * 8]);
#pragma unroll
      for (int mi = 0; mi < 8; mi++)
#pragma unroll
        for (int ni = 0; ni < 4; ni++)
          acc[mi][ni] = __builtin_amdgcn_mfma_f32_16x16x32_bf16(afr[mi], bfr[ni], acc[mi][ni], 0, 0, 0);
    }
    __syncthreads();
  }

  int colBase = n0 + (tid & 63) * 4;
  float b0 = 0.f, b1 = 0.f, b2 = 0.f, b3 = 0.f;
  if (colBase + 3 < VV) {
    float4 bv = *reinterpret_cast<const float4*>(bias + colBase);
    b0 = bv.x; b1 = bv.y; b2 = bv.z; b3 = bv.w;
  } else {
    if (colBase     < VV) b0 = bias[colBase];
    if (colBase + 1 < VV) b1 = bias[colBase + 1];
    if (colBase + 2 < VV) b2 = bias[colBase + 2];
  }
  int rw = tid >> 6;
  for (int ch = 0; ch < 4; ch++) {
    __syncthreads();
    if (wr == (ch >> 1)) {
      int mib = (ch & 1) * 4;
#pragma unroll
      for (int mi2 = 0; mi2 < 4; mi2++)
#pragma unroll
        for (int ni = 0; ni < 4; ni++) {
          int col = wc * 64 + ni * 16 + lr;
#pragma unroll
          for (int j = 0; j < 4; j++)
            Ep[(mi2 * 16 + lg * 4 + j) * 260 + col] = acc[mib + mi2][ni][j];
        }
    }
    __syncthreads();
#pragma unroll
    for (int pass = 0; pass < 8; pass++) {
      int r = pass * 8 + rw;
      f32x4 v = *reinterpret_cast<const f32x4*>(&Ep[r * 260 + (tid & 63) * 4]);
      v[0] += b0; v[1] += b1; v[2] += b2; v[3] += b3;
      float* dst = &C[(size_t)(m0 + ch * 64 + r) * VV + colBase];
      if (colBase + 3 < VV) {
        __builtin_nontemporal_store(v, reinterpret_cast<f32x4*>(dst));
      } else {
        if (colBase     < VV) __builtin_nontemporal_store(v[0], dst);
        if (colBase + 1 < VV) __builtin_nontemporal_store(v[1], dst + 1);
        if (colBase + 2 < VV) __builtin_nontemporal_store(v[2], dst + 2);
      }
    }
  }
}

// ---------------- flash attention v4: QBLK=64, balanced, 3 blocks/CU ----------
// (dropped kmAll table: mask computed from amask directly, L1-resident)
#define QBLK 64
#define KVB 64
__global__ __launch_bounds__(256) void attn_kernel(
    const bf16_t* __restrict__ qb, const bf16_t* __restrict__ kb,
    const bf16_t* __restrict__ vT, const int* __restrict__ amask,
    bf16_t* __restrict__ ab) {
  __shared__ bf16_t Qs[QBLK][72];
  __shared__ bf16_t Ps[QBLK][72];
  __shared__ __align__(16) bf16_t Ks[2][KVB * 64];
  __shared__ __align__(16) bf16_t Vs[2][KVB * 64];
  int tid = threadIdx.x, lane = tid & 63, w = tid >> 6;
  int lr = lane & 15, lg = lane >> 4;
  int bid = blockIdx.x;
  int bh = bid & 15;
  int qi = bid >> 4;
  int qq = (qi < 16) ? qi : 47 - qi;
  int q0 = qq * QBLK;
  int b = bh >> 3, h = bh & 7;
  const bf16_t* Qg = qb + (size_t)bh * SS * HD;
  const bf16_t* Kg = kb + (size_t)bh * SS * HD;
  const bf16_t* Vg = vT + (size_t)bh * HD * SS;
  const int* am = amask + b * SS;

  {
    int r = tid >> 2, c = (tid & 3) * 16;
    const uint4* s = reinterpret_cast<const uint4*>(Qg + (size_t)(q0 + r) * HD + c);
    uint4 a0 = s[0], a1 = s[1];
    *reinterpret_cast<uint4*>(&Qs[r][c])     = a0;
    *reinterpret_cast<uint4*>(&Qs[r][c + 8]) = a1;
  }

  auto stageKV = [&](int buf, int kv0) {
#pragma unroll
    for (int i = 0; i < 4; i++) {
      int c = w * 4 + i;
      if (c < 8) {
        gload_lds16(Kg + (size_t)(kv0 + (c >> 1) * 16 + lr) * HD + (c & 1) * 32 + lg * 8,
                    (char*)&Ks[buf][0] + c * 1024);
      } else {
        int cc = c - 8;
        gload_lds16(Vg + (size_t)((cc >> 1) * 16 + lr) * SS + kv0 + (cc & 1) * 32 + lg * 8,
                    (char*)&Vs[buf][0] + cc * 1024);
      }
    }
  };

  f32x4 o[4];
  f32x4 m_run, l_run;
  m_run = (f32x4){-1e30f, -1e30f, -1e30f, -1e30f};
  l_run = (f32x4){0.f, 0.f, 0.f, 0.f};
#pragma unroll
  for (int nd = 0; nd < 4; nd++) o[nd] = (f32x4){0.f, 0.f, 0.f, 0.f};

  stageKV(0, 0);
  __syncthreads();

  int ntile = qq + 1;
  for (int t = 0; t < ntile; t++) {
    int buf = t & 1;
    int kv0 = t * KVB;
    if (t + 1 < ntile) stageKV(buf ^ 1, kv0 + KVB);

    f32x4 sc[4];
#pragma unroll
    for (int ni = 0; ni < 4; ni++) sc[ni] = (f32x4){0.f, 0.f, 0.f, 0.f};
#pragma unroll
    for (int kk = 0; kk < 2; kk++) {
      bf16x8 af = *reinterpret_cast<const bf16x8*>(&Qs[w * 16 + lr][kk * 32 + lg * 8]);
      bf16x8 bf[4];
#pragma unroll
      for (int ni = 0; ni < 4; ni++)
        bf[ni] = *reinterpret_cast<const bf16x8*>(&Ks[buf][((ni << 1) + kk) * 512 + lane * 8]);
#pragma unroll
      for (int ni = 0; ni < 4; ni++)
        sc[ni] = __builtin_amdgcn_mfma_f32_16x16x32_bf16(af, bf[ni], sc[ni], 0, 0, 0);
    }

    {
      int qrb = q0 + w * 16 + lg * 4;
      float kmv[4];
#pragma unroll
      for (int ni = 0; ni < 4; ni++) kmv[ni] = am[kv0 + ni * 16 + lr] ? 0.f : -1e30f;
#pragma unroll
      for (int ni = 0; ni < 4; ni++) {
        int kg = kv0 + ni * 16 + lr;
#pragma unroll
        for (int j = 0; j < 4; j++) {
          float s = sc[ni][j] + kmv[ni];
          sc[ni][j] = (kg <= qrb + j) ? s : -1e30f;
        }
      }
      f32x4 rmax = sc[0];
#pragma unroll
      for (int ni = 1; ni < 4; ni++)
#pragma unroll
        for (int j = 0; j < 4; j++) rmax[j] = fmaxf(rmax[j], sc[ni][j]);
#pragma unroll
      for (int msk = 1; msk <= 8; msk <<= 1)
#pragma unroll
        for (int j = 0; j < 4; j++) rmax[j] = fmaxf(rmax[j], __shfl_xor(rmax[j], msk));
      f32x4 mnew, corr;
#pragma unroll
      for (int j = 0; j < 4; j++) {
        mnew[j] = fmaxf(m_run[j], rmax[j]);
        corr[j] = __expf(m_run[j] - mnew[j]);
      }
      m_run = mnew;
      f32x4 rs = (f32x4){0.f, 0.f, 0.f, 0.f};
#pragma unroll
      for (int ni = 0; ni < 4; ni++) {
#pragma unroll
        for (int j = 0; j < 4; j++) {
          float p = __expf(sc[ni][j] - mnew[j]);
          rs[j] += p;
          Ps[w * 16 + lg * 4 + j][ni * 16 + lr] = (bf16_t)p;
        }
      }
#pragma unroll
      for (int msk = 1; msk <= 8; msk <<= 1)
#pragma unroll
        for (int j = 0; j < 4; j++) rs[j] += __shfl_xor(rs[j], msk);
#pragma unroll
      for (int j = 0; j < 4; j++) l_run[j] = l_run[j] * corr[j] + rs[j];
#pragma unroll
      for (int nd = 0; nd < 4; nd++) o[nd] = o[nd] * corr;
    }

#pragma unroll
    for (int kc = 0; kc < 2; kc++) {
      bf16x8 pa = *reinterpret_cast<const bf16x8*>(&Ps[w * 16 + lr][kc * 32 + lg * 8]);
      bf16x8 vb[4];
#pragma unroll
      for (int nd = 0; nd < 4; nd++)
        vb[nd] = *reinterpret_cast<const bf16x8*>(&Vs[buf][((nd << 1) + kc) * 512 + lane * 8]);
#pragma unroll
      for (int nd = 0; nd < 4; nd++)
        o[nd] = __builtin_amdgcn_mfma_f32_16x16x32_bf16(pa, vb[nd], o[nd], 0, 0, 0);
    }
    asm volatile("s_waitcnt vmcnt(0)" ::: "memory");
    asm volatile("s_barrier" ::: "memory");
  }

  f32x4 linv;
#pragma unroll
  for (int j = 0; j < 4; j++) linv[j] = 1.f / l_run[j];
#pragma unroll
  for (int nd = 0; nd < 4; nd++)
#pragma unroll
    for (int j = 0; j < 4; j++) {
      int rowg = b * SS + q0 + w * 16 + lg * 4 + j;
      int col = h * HD + nd * 16 + lr;
      ab[(size_t)rowg * EE + col] = (bf16_t)(o[nd][j] * linv[j]);
    }
}

extern "C" void kernel_launch(void* const* d_in, const int* in_sizes, int n_in,
                              void* d_out, int out_size, void* d_ws, size_t ws_size,
                              hipStream_t stream) {
  const int*   ids   = (const int*)d_in[0];
  const int*   amask = (const int*)d_in[1];
  const float* emb   = (const float*)d_in[2];
  const float* Wq    = (const float*)d_in[3];
  const float* Wk    = (const float*)d_in[4];
  const float* Wv    = (const float*)d_in[5];
  const float* Wo    = (const float*)d_in[6];
  const float* ln1g  = (const float*)d_in[7];
  const float* ln1b  = (const float*)d_in[8];
  const float* ln2g  = (const float*)d_in[9];
  const float* ln2b  = (const float*)d_in[10];
  const float* fw1   = (const float*)d_in[11];
  const float* fb1   = (const float*)d_in[12];
  const float* fw2   = (const float*)d_in[13];
  const float* fb2   = (const float*)d_in[14];
  const float* lnfg  = (const float*)d_in[15];
  const float* lnfb  = (const float*)d_in[16];
  const float* Wout  = (const float*)d_in[17];
  const float* bout  = (const float*)d_in[18];
  float* out = (float*)d_out;

  float*  x     = (float*)d_ws;
  bf16_t* xn    = (bf16_t*)((char*)d_ws + (8u << 20));
  bf16_t* WoutT = (bf16_t*)((char*)d_ws + (12u << 20));
  char* sc = (char*)d_out;
  bf16_t* qbuf = (bf16_t*)(sc);
  bf16_t* kbuf = (bf16_t*)(sc + 4194304);
  bf16_t* vTb  = (bf16_t*)(sc + 8388608);
  bf16_t* ab   = (bf16_t*)(sc + 12582912);
  bf16_t* hb   = (bf16_t*)(sc + 16777216);
  bf16_t* Wqkv = (bf16_t*)(sc + 33554432);
  bf16_t* WoT  = (bf16_t*)(sc + 39845888);
  bf16_t* W1T  = (bf16_t*)(sc + 41943040);
  bf16_t* W2T  = (bf16_t*)(sc + 50331648);

  wconv_qkv_kernel<<<dim3(8, 1, 96), 256, 0, stream>>>(Wq, Wk, Wv, Wqkv);
  wconv_kernel<<<dim3(8, 8, LL), 256, 0, stream>>>(Wo, WoT, 512, 512, 512,
                                                   512L * 512, 512L * 512);
  wconv_kernel<<<dim3(8, 32, LL), 256, 0, stream>>>(fw1, W1T, 2048, 512, 2048,
                                                    512L * 2048, 2048L * 512);
  wconv_kernel<<<dim3(32, 8, LL), 256, 0, stream>>>(fw2, W2T, 512, 2048, 512,
                                                    2048L * 512, 512L * 2048);
  wconv_kernel<<<dim3(8, VPAD2 / 64, 1), 256, 0, stream>>>(Wout, WoutT, VV, 512, VV, 0, 0);

  embed_kernel<<<NTOK * EE / 256, 256, 0, stream>>>(ids, emb, x);

  for (int l = 0; l < LL; l++) {
    ln_kernel<<<NTOK / 4, 256, 0, stream>>>(x, xn, ln1g + l * EE, ln1b + l * EE);
    gemm_bf16<0, 128><<<dim3(12, 32), 256, 0, stream>>>(xn, Wqkv + (size_t)l * 1536 * 512,
        NTOK, 1536, 512, nullptr, nullptr, nullptr, qbuf, kbuf, vTb);
    attn_kernel<<<dim3(512), 256, 0, stream>>>(qbuf, kbuf, vTb, amask, ab);
    gemm_bf16<2, 32><<<dim3(4, 128), 256, 0, stream>>>(ab, WoT + (size_t)l * 512 * 512,
        NTOK, 512, 512, nullptr, x, nullptr, nullptr, nullptr, nullptr);
    ln_kernel<<<NTOK / 4, 256, 0, stream>>>(x, xn, ln2g + l * EE, ln2b + l * EE);
    gemm_bf16<1, 128><<<dim3(16, 32), 256, 0, stream>>>(xn, W1T + (size_t)l * 2048 * 512,
        NTOK, 2048, 512, fb1 + l * 2048, nullptr, hb, nullptr, nullptr, nullptr);
    gemm_bf16<2, 32><<<dim3(4, 128), 256, 0, stream>>>(hb, W2T + (size_t)l * 512 * 2048,
        NTOK, 512, 2048, fb2 + l * EE, x, nullptr, nullptr, nullptr, nullptr);
  }
  ln_kernel<<<NTOK / 4, 256, 0, stream>>>(x, xn, lnfg, lnfb);
  gemm256_out<<<dim3(16 * (VPAD2 / 256)), 512, 0, stream>>>(xn, WoutT, bout, out);
}